// Round 8
// baseline (221.436 us; speedup 1.0000x reference)
//
#include <hip/hip_runtime.h>

#define KCODES 1024
#define CDIM   256
#define SP     16384           // D*H*W
#define ZQTOT  16777216        // B*C*D*H*W
#define NQ     65536           // B*D*H*W
#define BSTRIDE 4194304        // C*SP
#define MAX_AMB 12288
#define LOSS_SCALE 33554432.0  // 2^25 fixed-point deterministic loss
#define KEYMASK 0xFFFFFC00u
#define AMB_THR 6.0e-4f
#define BIAS    0.25f

#define QT3    64              // queries per block
#define NIT    16              // iterations (64 codes each)
#define CROWB  528             // padded LDS bytes per code row (33*16)
#define BTILEB 33792           // 64*528

using f32x4  = __attribute__((ext_vector_type(4)))  float;
using bf16x8 = __attribute__((ext_vector_type(8)))  short;

__device__ __forceinline__ unsigned short f2bf(float x) {   // RNE f32->bf16
    unsigned u = __float_as_uint(x);
    u += 0x7fffu + ((u >> 16) & 1u);
    return (unsigned short)(u >> 16);
}
__device__ __forceinline__ float keyval(unsigned k) {       // biased keys are positive floats
    return __uint_as_float(k & KEYMASK);
}
__device__ __forceinline__ unsigned umn(unsigned a, unsigned b){ return a < b ? a : b; }
__device__ __forceinline__ unsigned umx(unsigned a, unsigned b){ return a > b ? a : b; }

// ---- numpy pairwise_sum replication (base case n=128, 8 accumulators) ----
__device__ __forceinline__ float pw128_sq(const float* a) {
    float r[8];
    #pragma unroll
    for (int j = 0; j < 8; ++j) r[j] = __fmul_rn(a[j], a[j]);
    for (int i = 8; i < 128; i += 8) {
        #pragma unroll
        for (int j = 0; j < 8; ++j) r[j] = __fadd_rn(r[j], __fmul_rn(a[i+j], a[i+j]));
    }
    return __fadd_rn(__fadd_rn(__fadd_rn(r[0], r[1]), __fadd_rn(r[2], r[3])),
                     __fadd_rn(__fadd_rn(r[4], r[5]), __fadd_rn(r[6], r[7])));
}
__device__ __forceinline__ float pairwise256_sq(const float* a) {
    return __fadd_rn(pw128_sq(a), pw128_sq(a + 128));
}
// np.einsum SSE path: 4 mod-4 accumulators, separate mul/add roundings
__device__ __forceinline__ float np_dot256(const float* zr, const float* er) {
    float a0 = 0.f, a1 = 0.f, a2 = 0.f, a3 = 0.f;
    for (int i8 = 0; i8 < 256; i8 += 8) {
        a0 = __fadd_rn(a0, __fmul_rn(zr[i8+0], er[i8+0]));
        a1 = __fadd_rn(a1, __fmul_rn(zr[i8+1], er[i8+1]));
        a2 = __fadd_rn(a2, __fmul_rn(zr[i8+2], er[i8+2]));
        a3 = __fadd_rn(a3, __fmul_rn(zr[i8+3], er[i8+3]));
        a0 = __fadd_rn(a0, __fmul_rn(zr[i8+4], er[i8+4]));
        a1 = __fadd_rn(a1, __fmul_rn(zr[i8+5], er[i8+5]));
        a2 = __fadd_rn(a2, __fmul_rn(zr[i8+6], er[i8+6]));
        a3 = __fadd_rn(a3, __fmul_rn(zr[i8+7], er[i8+7]));
    }
    return __fadd_rn(__fadd_rn(a0, a1), __fadd_rn(a2, a3));
}

// ---------------- pre-pass: emb -> bf16 + BIASED esq ----------------
__global__ __launch_bounds__(64)
void vq_prep(const float* __restrict__ emb, unsigned short* __restrict__ embh,
             float* __restrict__ esq_g) {
    const int k = blockIdx.x;
    const int l = threadIdx.x;
    float4 v = ((const float4*)(emb + (size_t)k * CDIM))[l];
    float s = v.x*v.x + v.y*v.y + v.z*v.z + v.w*v.w;
    unsigned short h0=f2bf(v.x), h1=f2bf(v.y), h2=f2bf(v.z), h3=f2bf(v.w);
    uint2 hh; hh.x = (unsigned)h0 | ((unsigned)h1<<16); hh.y = (unsigned)h2 | ((unsigned)h3<<16);
    *(uint2*)&embh[(size_t)k*CDIM + l*4] = hh;
    #pragma unroll
    for (int off = 32; off > 0; off >>= 1) s += __shfl_down(s, off, 64);
    if (l == 0) esq_g[k] = s + BIAS;   // biased: keeps all scores positive
}

// ---------------- MFMA main: 16x16x32, A-in-regs(8), B LDS-dbuf ----------------
__global__ __launch_bounds__(256, 2)
void vq_main_mfma(const float* __restrict__ z, const float* __restrict__ emb,
                  const unsigned short* __restrict__ embh,
                  const float* __restrict__ esq_g,
                  float* __restrict__ out, unsigned long long* __restrict__ loss_acc,
                  unsigned int* __restrict__ amb_cnt, uint4* __restrict__ wl4) {
    __shared__ __align__(16) unsigned char smem[73232];
    float*    esql = (float*)(smem + 2*BTILEB);         // 4KB  (biased esq)
    unsigned* top1 = (unsigned*)(smem + 71680);         // 4 x 256B
    unsigned* top2 = top1 + 64;
    unsigned* top3 = top2 + 64;
    unsigned* top4 = top3 + 64;
    float*    zsql = (float*)(smem + 72704);            // 256B
    int*      fidx = (int*)(smem + 72960);              // 256B

    const int t   = threadIdx.x;
    const int l   = t & 63;
    const int w   = t >> 6;
    const int g   = l >> 4;      // k-quarter selector
    const int lr  = l & 15;      // A row / B col selector
    const int n0  = blockIdx.x * QT3;
    const int b   = n0 >> 14;
    const int sp0 = n0 & 16383;
    const int wq0 = w * 16;
    const float* zb = z + (size_t)b * BSTRIDE + sp0 + wq0 + lr;
    const char* ebase = (const char*)embh;

    // ---- stage B tile 0: global -> reg -> LDS buf0 ----
    uint4 st[8];
    #pragma unroll
    for (int k = 0; k < 8; ++k)
        st[k] = *(const uint4*)(ebase + (size_t)(t + k*256) * 16);
    #pragma unroll
    for (int k = 0; k < 8; ++k) {
        const int idx = t + k*256;
        *(uint4*)(smem + (idx >> 5)*CROWB + (idx & 31)*16) = st[k];
    }

    // ---- A fragments (8 x bf16x8, K=256) + zsq partial ----
    bf16x8 A[8];
    float zsq_p = 0.f;
    #pragma unroll
    for (int ks = 0; ks < 8; ++ks) {
        float v[8];
        #pragma unroll
        for (int j = 0; j < 8; ++j) v[j] = zb[(size_t)(ks*32 + g*8 + j) * SP];
        bf16x8 a;
        #pragma unroll
        for (int j = 0; j < 8; ++j) {
            zsq_p += v[j] * v[j];
            a[j] = (short)f2bf(v[j]);
        }
        A[ks] = a;
    }
    zsq_p += __shfl_xor(zsq_p, 16, 64);
    zsq_p += __shfl_xor(zsq_p, 32, 64);
    if (g == 0) zsql[wq0 + lr] = zsq_p;
    for (int k = t; k < KCODES; k += 256) esql[k] = esq_g[k];
    __syncthreads();

    unsigned m1[4], m2[4], m3[4];
    #pragma unroll
    for (int j = 0; j < 4; ++j) { m1[j]=0xFFFFFFFFu; m2[j]=0xFFFFFFFFu; m3[j]=0xFFFFFFFFu; }

    int cur = 0;
    for (int it = 0; it < NIT; ++it) {
        // prefetch next B tile into regs (issue early)
        if (it + 1 < NIT) {
            #pragma unroll
            for (int k = 0; k < 8; ++k)
                st[k] = *(const uint4*)(ebase + (size_t)(it+1)*32768 + (size_t)(t + k*256)*16);
        }
        float es[4];
        #pragma unroll
        for (int nt = 0; nt < 4; ++nt) es[nt] = esql[it*64 + nt*16 + lr];

        const unsigned char* bb = smem + cur*BTILEB + lr*CROWB + g*16;
        f32x4 acc[4];
        #pragma unroll
        for (int nt = 0; nt < 4; ++nt) acc[nt] = f32x4{0.f,0.f,0.f,0.f};
        #pragma unroll
        for (int ks = 0; ks < 8; ++ks) {
            #pragma unroll
            for (int nt = 0; nt < 4; ++nt) {     // 4 independent MFMA chains
                const bf16x8 Bv = *(const bf16x8*)(bb + nt*16*CROWB + ks*64);
                acc[nt] = __builtin_amdgcn_mfma_f32_16x16x32_bf16(A[ks], Bv, acc[nt], 0, 0, 0);
            }
        }
        // fold: biased score is positive -> raw bits monotone; 7 VALU/score
        #pragma unroll
        for (int nt = 0; nt < 4; ++nt) {
            const unsigned kc = (unsigned)(it*64 + nt*16 + lr);
            #pragma unroll
            for (int j = 0; j < 4; ++j) {
                const float s = __builtin_fmaf(-2.0f, acc[nt][j], es[nt]);
                const unsigned p = (__float_as_uint(s) & KEYMASK) | kc;
                const unsigned x = umx(m1[j], p); m1[j] = umn(m1[j], p);
                const unsigned y = umx(m2[j], x); m2[j] = umn(m2[j], x);
                m3[j] = umn(m3[j], y);
            }
        }
        __syncthreads();                 // all reads of cur buffer done
        if (it + 1 < NIT) {              // write next tile (write late)
            #pragma unroll
            for (int k = 0; k < 8; ++k) {
                const int idx = t + k*256;
                *(uint4*)(smem + (cur^1)*BTILEB + (idx >> 5)*CROWB + (idx & 31)*16) = st[k];
            }
        }
        __syncthreads();
        cur ^= 1;
    }

    // ---- butterfly across 16 lr-lanes per group: top-3/lane -> exact top-4 ----
    #pragma unroll
    for (int j = 0; j < 4; ++j) {
        unsigned t1 = m1[j], t2 = m2[j], t3 = m3[j], t4 = 0xFFFFFFFFu;
        #pragma unroll
        for (int m = 1; m < 16; m <<= 1) {
            const unsigned b1 = (unsigned)__shfl_xor((int)t1, m, 64);
            const unsigned b2 = (unsigned)__shfl_xor((int)t2, m, 64);
            const unsigned b3 = (unsigned)__shfl_xor((int)t3, m, 64);
            const unsigned b4 = (unsigned)__shfl_xor((int)t4, m, 64);
            #define INS(v) { unsigned x_=umx(t1,(v)); t1=umn(t1,(v)); \
                             unsigned y_=umx(t2,x_);  t2=umn(t2,x_);  \
                             unsigned z_=umx(t3,y_);  t3=umn(t3,y_);  \
                             t4=umn(t4,z_); }
            INS(b1); INS(b2); INS(b3); INS(b4);
            #undef INS
        }
        if (lr == 0) {
            const int qq = wq0 + g*4 + j;
            top1[qq] = t1; top2[qq] = t2; top3[qq] = t3; top4[qq] = t4;
        }
    }
    __syncthreads();

    // ---- finalize: idx, ambiguity enqueue, loss (wave 0) ----
    if (t < QT3) {
        const unsigned k1 = top1[t], k2 = top2[t], k3 = top3[t], k4 = top4[t];
        const int I1 = (int)(k1 & 1023u);
        fidx[t] = I1;
        out[ZQTOT + 1 + n0 + t] = (float)I1;
        const float s0 = keyval(k1) - BIAS;
        if (keyval(k2) - keyval(k1) < AMB_THR) {
            unsigned pos = atomicAdd(amb_cnt, 1u);
            if (pos < MAX_AMB)
                wl4[pos] = make_uint4((unsigned)(n0 + t),
                                      (k1 & 1023u) | ((k2 & 1023u) << 16),
                                      (k3 & 1023u) | ((k4 & 1023u) << 16), 0u);
        }
        float lq = zsql[t] + s0;         // ||z-e||^2 = zsq + (esq - 2 dot)
        #pragma unroll
        for (int off = 32; off > 0; off >>= 1) lq += __shfl_down(lq, off, 64);
        if (t == 0)
            atomicAdd(loss_acc, (unsigned long long)(long long)((double)lq * LOSS_SCALE));
    }
    __syncthreads();

    // ---- z_q write: stream emb[fidx] rows (STE output == e, tol 20.48) ----
    {
        const int q  = t & 63;
        const int dh = t >> 6;           // wave w writes dims [64w, 64w+64)
        const int fq = fidx[q];
        const float4* ev = (const float4*)(emb + (size_t)fq * CDIM + dh * 64);
        float* ob = out + (size_t)b * BSTRIDE + (size_t)dh * 64 * SP + sp0 + q;
        #pragma unroll
        for (int i = 0; i < 16; ++i) {
            const float4 v = ev[i];
            float* o = ob + (size_t)(i * 4) * SP;
            o[0]            = v.x;
            o[SP]           = v.y;
            o[2*SP]         = v.z;
            o[(size_t)3*SP] = v.w;
        }
    }
}

// ---------------- fixup: wave-parallel np-exact eval of <=4 candidates ----------------
__global__ __launch_bounds__(64)
void vq_fix_cand(const float* __restrict__ z, const float* __restrict__ emb,
                 float* __restrict__ out, const unsigned int* __restrict__ amb_cnt,
                 const uint4* __restrict__ wl4) {
    __shared__ float zrow[CDIM];
    __shared__ float erow[4][CDIM];
    __shared__ float dsh[4], esh[4];
    __shared__ float zss;

    unsigned cnt = *amb_cnt; if (cnt > MAX_AMB) cnt = MAX_AMB;
    if (blockIdx.x >= cnt) return;
    const uint4 e = wl4[blockIdx.x];
    const int n = (int)e.x;
    const int b = n >> 14, sp = n & 16383;
    int codes[4] = { (int)(e.y & 1023u), (int)((e.y >> 16) & 1023u),
                     (int)(e.z & 1023u), (int)((e.z >> 16) & 1023u) };
    const int l = threadIdx.x;

    #pragma unroll
    for (int i = 0; i < 4; ++i) {
        const int c = l + 64*i;
        zrow[c] = z[(size_t)b * BSTRIDE + (size_t)c * SP + sp];
    }
    {
        const int r = l >> 4, c0 = (l & 15) * 16;
        const float4* src = (const float4*)(emb + (size_t)codes[r] * CDIM + c0);
        float4* dst = (float4*)&erow[r][c0];
        #pragma unroll
        for (int i = 0; i < 4; ++i) dst[i] = src[i];
    }
    __syncthreads();

    const int role = l >> 4, rr = (l >> 2) & 3, a = l & 3;
    if (role == 0) {
        // np.einsum dots: lane (rr,a) runs the mod-4 accumulator 'a' for candidate rr
        const float* er = erow[rr];
        float acc = __fmul_rn(zrow[a], er[a]);
        for (int i = 1; i < 64; ++i)
            acc = __fadd_rn(acc, __fmul_rn(zrow[4*i + a], er[4*i + a]));
        const float u = __fadd_rn(acc, __shfl_xor(acc, 1, 64));
        const float d = __fadd_rn(u,   __shfl_xor(u,   2, 64));  // (a0+a1)+(a2+a3)
        if (a == 0) dsh[rr] = d;
    } else if (role == 1 || (role == 2 && rr == 0)) {
        // np pairwise_sum of squares: chains j=a, j=a+4, both 128-halves
        const float* src = (role == 1) ? erow[rr] : zrow;
        float pA = __fmul_rn(src[a],       src[a]);
        float pB = __fmul_rn(src[a+4],     src[a+4]);
        float qA = __fmul_rn(src[128+a],   src[128+a]);
        float qB = __fmul_rn(src[128+a+4], src[128+a+4]);
        #pragma unroll 4
        for (int i = 1; i < 16; ++i) {
            pA = __fadd_rn(pA, __fmul_rn(src[8*i+a],       src[8*i+a]));
            pB = __fadd_rn(pB, __fmul_rn(src[8*i+a+4],     src[8*i+a+4]));
            qA = __fadd_rn(qA, __fmul_rn(src[128+8*i+a],   src[128+8*i+a]));
            qB = __fadd_rn(qB, __fmul_rn(src[128+8*i+a+4], src[128+8*i+a+4]));
        }
        float uA = __fadd_rn(pA, __shfl_xor(pA, 1, 64));
        float vA = __fadd_rn(uA, __shfl_xor(uA, 2, 64));   // (r0+r1)+(r2+r3)
        float uB = __fadd_rn(pB, __shfl_xor(pB, 1, 64));
        float vB = __fadd_rn(uB, __shfl_xor(uB, 2, 64));   // (r4+r5)+(r6+r7)
        const float h0 = __fadd_rn(vA, vB);                // pw128 half0
        float uC = __fadd_rn(qA, __shfl_xor(qA, 1, 64));
        float vC = __fadd_rn(uC, __shfl_xor(uC, 2, 64));
        float uD = __fadd_rn(qB, __shfl_xor(qB, 1, 64));
        float vD = __fadd_rn(uD, __shfl_xor(uD, 2, 64));
        const float h1 = __fadd_rn(vC, vD);                // pw128 half1
        const float stot = __fadd_rn(h0, h1);
        if (a == 0) { if (role == 1) esh[rr] = stot; else zss = stot; }
    }
    __syncthreads();
    if (l == 0) {
        float bd = 3.4e38f; int bk = KCODES;
        #pragma unroll
        for (int i = 0; i < 4; ++i) {
            const float d = __fsub_rn(__fadd_rn(zss, esh[i]), __fmul_rn(2.0f, dsh[i]));
            if (d < bd || (d == bd && codes[i] < bk)) { bd = d; bk = codes[i]; }
        }
        out[ZQTOT + 1 + n] = (float)bk;   // np.argmin first-index semantics
    }
}

// ---------------- fallback (round-3 proven path, used if ws too small) ----------------
__global__ __launch_bounds__(256)
void vq_main_basic(const float* __restrict__ z, const float* __restrict__ emb,
                   float* __restrict__ out, unsigned long long* __restrict__ loss_acc,
                   unsigned int* __restrict__ amb_cnt, unsigned int* __restrict__ wl) {
    __shared__ float zlz[64 * CDIM];
    __shared__ float esq[KCODES];
    __shared__ float m1s[4][64], m2s[4][64];
    __shared__ int   i1s[4][64];
    __shared__ int   fidx[64];
    __shared__ float lsum[4];

    const int t  = threadIdx.x;
    const int q  = t & 63;
    const int w  = __builtin_amdgcn_readfirstlane(t >> 6);
    const int qs = q & 7;
    const int n0 = blockIdx.x * 64;
    const int b  = n0 >> 14;
    const int sp0 = n0 & 16383;
    const float* zb = z + (size_t)b * BSTRIDE;

    #pragma unroll 4
    for (int i = 0; i < 64; ++i) {
        int c = (t >> 6) * 64 + i;
        float v = zb[(size_t)c * SP + sp0 + q];
        zlz[q * CDIM + ((((c >> 2) ^ qs) << 2) | (c & 3))] = v;
    }
    for (int k = t; k < KCODES; k += 256) {
        const float4* er = (const float4*)(emb + (size_t)k * CDIM);
        float s = 0.f;
        for (int c4 = 0; c4 < 64; ++c4) {
            float4 e = er[c4];
            s += e.x*e.x + e.y*e.y + e.z*e.z + e.w*e.w;
        }
        esq[k] = s;
    }
    __syncthreads();

    float m1 = 3.4e38f, m2 = 3.4e38f; int i1 = 0;
    const float* zrow = zlz + q * CDIM;
    const int kbase = w * 256;
    for (int kk = 0; kk < 256; kk += 8) {
        const int k0 = kbase + kk;
        float acc[8] = {0,0,0,0,0,0,0,0};
        for (int c4 = 0; c4 < 64; ++c4) {
            float4 zv = *(const float4*)(zrow + ((c4 ^ qs) << 2));
            #pragma unroll
            for (int j = 0; j < 8; ++j) {
                float4 ev = *(const float4*)(emb + (size_t)(k0 + j) * CDIM + (c4 << 2));
                acc[j] += zv.x*ev.x + zv.y*ev.y + zv.z*ev.z + zv.w*ev.w;
            }
        }
        #pragma unroll
        for (int j = 0; j < 8; ++j) {
            float s = esq[k0 + j] - 2.0f * acc[j];
            if (s < m1)      { m2 = m1; m1 = s; i1 = k0 + j; }
            else if (s < m2) { m2 = s; }
        }
    }
    m1s[w][q] = m1; m2s[w][q] = m2; i1s[w][q] = i1;
    __syncthreads();

    if (t < 64) {
        float M1 = 3.4e38f, M2 = 3.4e38f; int I1 = 0;
        for (int g = 0; g < 4; ++g) {
            float v1 = m1s[g][t], v2 = m2s[g][t];
            int   a1 = i1s[g][t];
            if (v1 < M1) { M2 = M1; M1 = v1; I1 = a1; }
            else if (v1 < M2) { M2 = v1; }
            if (v2 < M2) { M2 = v2; }
        }
        if (M2 - M1 < 1.5e-4f) {
            unsigned pos = atomicAdd(amb_cnt, 1u);
            if (pos < MAX_AMB) wl[pos] = n0 + t;
        }
        fidx[t] = I1;
        out[ZQTOT + 1 + n0 + t] = (float)I1;
    }
    __syncthreads();

    const int fq = fidx[q];
    const float* eq = emb + (size_t)fq * CDIM;
    float ls = 0.f;
    #pragma unroll 4
    for (int i = 0; i < 64; ++i) {
        int c = (t >> 6) * 64 + i;
        float zv = zrow[((((c >> 2) ^ qs) << 2) | (c & 3))];
        float ev = eq[c];
        float d = ev - zv;
        ls += d * d;
        out[(size_t)b * BSTRIDE + (size_t)c * SP + sp0 + q] = zv + d;
    }
    #pragma unroll
    for (int off = 32; off > 0; off >>= 1) ls += __shfl_down(ls, off, 64);
    if (q == 0) lsum[w] = ls;
    __syncthreads();
    if (t == 0) {
        float tot = lsum[0] + lsum[1] + lsum[2] + lsum[3];
        atomicAdd(loss_acc, (unsigned long long)(long long)((double)tot * LOSS_SCALE));
    }
}

__global__ __launch_bounds__(256)
void vq_fix_np(const float* __restrict__ z, const float* __restrict__ emb,
               float* __restrict__ out, const unsigned int* __restrict__ amb_cnt,
               const unsigned int* __restrict__ wl) {
    __shared__ float zrow[CDIM];
    __shared__ float zsq_sh;
    __shared__ float rd[256];
    __shared__ int   rk[256];

    unsigned cnt = *amb_cnt; if (cnt > MAX_AMB) cnt = MAX_AMB;
    if (blockIdx.x >= cnt) return;
    const int n = (int)wl[blockIdx.x];
    const int b = n >> 14, sp = n & 16383;
    const int t = threadIdx.x;

    zrow[t] = z[(size_t)b * BSTRIDE + (size_t)t * SP + sp];
    __syncthreads();
    if (t == 0) zsq_sh = pairwise256_sq(zrow);
    __syncthreads();
    const float zsq = zsq_sh;

    float bestd = 3.4e38f; int bestk = KCODES;
    for (int j = 0; j < 4; ++j) {
        const int k = t + 256 * j;
        const float* er = emb + (size_t)k * CDIM;
        const float dot = np_dot256(zrow, er);
        const float es  = pairwise256_sq(er);
        const float d   = __fsub_rn(__fadd_rn(zsq, es), __fmul_rn(2.0f, dot));
        if (d < bestd || (d == bestd && k < bestk)) { bestd = d; bestk = k; }
    }
    rd[t] = bestd; rk[t] = bestk;
    __syncthreads();
    for (int s = 128; s > 0; s >>= 1) {
        if (t < s) {
            float od = rd[t + s]; int ok = rk[t + s];
            if (od < rd[t] || (od == rd[t] && ok < rk[t])) { rd[t] = od; rk[t] = ok; }
        }
        __syncthreads();
    }
    if (t == 0) out[ZQTOT + 1 + n] = (float)rk[0];
}

__global__ void vq_final(const unsigned long long* __restrict__ acc, float* __restrict__ out) {
    if (threadIdx.x == 0 && blockIdx.x == 0) {
        double mse = (double)(long long)acc[0] / LOSS_SCALE / (double)ZQTOT;
        out[ZQTOT] = (float)(mse * 1.25);   // (1 + beta) * mse
    }
}

extern "C" void kernel_launch(void* const* d_in, const int* in_sizes, int n_in,
                              void* d_out, int out_size, void* d_ws, size_t ws_size,
                              hipStream_t stream) {
    const float* z   = (const float*)d_in[0];
    const float* emb = (const float*)d_in[1];
    float* out = (float*)d_out;

    unsigned long long* loss_acc = (unsigned long long*)d_ws;
    unsigned int* amb_cnt = (unsigned int*)((char*)d_ws + 8);
    const size_t WL4_OFF  = 64;
    const size_t ESQ_OFF  = (WL4_OFF + (size_t)MAX_AMB * 16 + 255) & ~(size_t)255;
    const size_t EMBH_OFF = (ESQ_OFF + (size_t)KCODES * 4 + 255) & ~(size_t)255;
    const size_t WS_NEED  = EMBH_OFF + (size_t)KCODES * CDIM * 2;

    hipMemsetAsync(d_ws, 0, 16, stream);
    if (ws_size >= WS_NEED) {
        uint4* wl4 = (uint4*)((char*)d_ws + WL4_OFF);
        float* esq_g = (float*)((char*)d_ws + ESQ_OFF);
        unsigned short* embh = (unsigned short*)((char*)d_ws + EMBH_OFF);
        vq_prep<<<dim3(KCODES), dim3(64), 0, stream>>>(emb, embh, esq_g);
        vq_main_mfma<<<dim3(NQ / QT3), dim3(256), 0, stream>>>(z, emb, embh, esq_g,
                                                               out, loss_acc, amb_cnt, wl4);
        vq_fix_cand<<<dim3(MAX_AMB), dim3(64), 0, stream>>>(z, emb, out, amb_cnt, wl4);
    } else {
        unsigned int* wl = (unsigned int*)((char*)d_ws + WL4_OFF);
        vq_main_basic<<<dim3(NQ / 64), dim3(256), 0, stream>>>(z, emb, out, loss_acc, amb_cnt, wl);
        vq_fix_np<<<dim3(MAX_AMB), dim3(256), 0, stream>>>(z, emb, out, amb_cnt, wl);
    }
    vq_final<<<dim3(1), dim3(64), 0, stream>>>(loss_acc, out);
}

// Round 9
// 210.421 us; speedup vs baseline: 1.0523x; 1.0523x over previous
//
#include <hip/hip_runtime.h>

#define KCODES 1024
#define CDIM   256
#define SP     16384           // D*H*W
#define ZQTOT  16777216        // B*C*D*H*W
#define NQ     65536           // B*D*H*W
#define BSTRIDE 4194304        // C*SP
#define MAX_AMB 12288
#define LOSS_SCALE 33554432.0  // 2^25 fixed-point deterministic loss
#define KEYMASK 0xFFFFFC00u
#define AMB_THR 6.0e-4f
#define BIAS    0.25f

#define QT     64              // queries per block
#define NTILE  32              // 32 code-tiles of 32 codes
#define CROWB  528             // padded LDS bytes per code row (33*16)
#define TILEB  16896           // 32*528

using f32x4  = __attribute__((ext_vector_type(4)))  float;
using f32x16 = __attribute__((ext_vector_type(16))) float;
using bf16x8 = __attribute__((ext_vector_type(8)))  short;

__device__ __forceinline__ unsigned short f2bf(float x) {   // RNE f32->bf16
    unsigned u = __float_as_uint(x);
    u += 0x7fffu + ((u >> 16) & 1u);
    return (unsigned short)(u >> 16);
}
__device__ __forceinline__ float keyval(unsigned k) {       // biased keys are positive floats
    return __uint_as_float(k & KEYMASK);
}
__device__ __forceinline__ unsigned umn(unsigned a, unsigned b){ return a < b ? a : b; }
__device__ __forceinline__ unsigned umx(unsigned a, unsigned b){ return a > b ? a : b; }

// ---- numpy pairwise_sum replication (base case n=128, 8 accumulators) ----
__device__ __forceinline__ float pw128_sq(const float* a) {
    float r[8];
    #pragma unroll
    for (int j = 0; j < 8; ++j) r[j] = __fmul_rn(a[j], a[j]);
    for (int i = 8; i < 128; i += 8) {
        #pragma unroll
        for (int j = 0; j < 8; ++j) r[j] = __fadd_rn(r[j], __fmul_rn(a[i+j], a[i+j]));
    }
    return __fadd_rn(__fadd_rn(__fadd_rn(r[0], r[1]), __fadd_rn(r[2], r[3])),
                     __fadd_rn(__fadd_rn(r[4], r[5]), __fadd_rn(r[6], r[7])));
}
__device__ __forceinline__ float pairwise256_sq(const float* a) {
    return __fadd_rn(pw128_sq(a), pw128_sq(a + 128));
}
// np.einsum SSE path: 4 mod-4 accumulators, separate mul/add roundings
__device__ __forceinline__ float np_dot256(const float* zr, const float* er) {
    float a0 = 0.f, a1 = 0.f, a2 = 0.f, a3 = 0.f;
    for (int i8 = 0; i8 < 256; i8 += 8) {
        a0 = __fadd_rn(a0, __fmul_rn(zr[i8+0], er[i8+0]));
        a1 = __fadd_rn(a1, __fmul_rn(zr[i8+1], er[i8+1]));
        a2 = __fadd_rn(a2, __fmul_rn(zr[i8+2], er[i8+2]));
        a3 = __fadd_rn(a3, __fmul_rn(zr[i8+3], er[i8+3]));
        a0 = __fadd_rn(a0, __fmul_rn(zr[i8+4], er[i8+4]));
        a1 = __fadd_rn(a1, __fmul_rn(zr[i8+5], er[i8+5]));
        a2 = __fadd_rn(a2, __fmul_rn(zr[i8+6], er[i8+6]));
        a3 = __fadd_rn(a3, __fmul_rn(zr[i8+7], er[i8+7]));
    }
    return __fadd_rn(__fadd_rn(a0, a1), __fadd_rn(a2, a3));
}

// ---------------- pre-pass: emb -> bf16 + BIASED esq ----------------
__global__ __launch_bounds__(64)
void vq_prep(const float* __restrict__ emb, unsigned short* __restrict__ embh,
             float* __restrict__ esq_g) {
    const int k = blockIdx.x;
    const int l = threadIdx.x;
    float4 v = ((const float4*)(emb + (size_t)k * CDIM))[l];
    float s = v.x*v.x + v.y*v.y + v.z*v.z + v.w*v.w;
    unsigned short h0=f2bf(v.x), h1=f2bf(v.y), h2=f2bf(v.z), h3=f2bf(v.w);
    uint2 hh; hh.x = (unsigned)h0 | ((unsigned)h1<<16); hh.y = (unsigned)h2 | ((unsigned)h3<<16);
    *(uint2*)&embh[(size_t)k*CDIM + l*4] = hh;
    #pragma unroll
    for (int off = 32; off > 0; off >>= 1) s += __shfl_down(s, off, 64);
    if (l == 0) esq_g[k] = s + BIAS;   // biased: keeps all scores positive
}

// ---------------- MFMA main: 32x32x16, A-in-regs, B LDS-dbuf, 1 barrier/iter ----------------
__global__ __launch_bounds__(128, 2)
void vq_main_mfma(const float* __restrict__ z, const float* __restrict__ emb,
                  const unsigned short* __restrict__ embh,
                  const float* __restrict__ esq_g,
                  float* __restrict__ out, unsigned long long* __restrict__ loss_acc,
                  unsigned int* __restrict__ amb_cnt, uint4* __restrict__ wl4) {
    __shared__ __align__(16) unsigned char smem[35392];
    unsigned* top1 = (unsigned*)(smem + 2*TILEB);     // 64 u32 each
    unsigned* top2 = top1 + 64;
    unsigned* top3 = top2 + 64;
    unsigned* top4 = top3 + 64;
    float*    zsql = (float*)(top4 + 64);             // 64 f32
    int*      fidx = (int*)(zsql + 64);               // 64 i32

    const int t    = threadIdx.x;                     // 128 threads = 2 waves
    const int l    = t & 63;
    const int w    = t >> 6;
    const int half = l >> 5;
    const int lr   = l & 31;
    const int n0   = blockIdx.x * QT;
    const int b    = n0 >> 14;
    const int sp0  = n0 & 16383;
    const int wq0  = w * 32;
    const float* zb = z + (size_t)b * BSTRIDE + sp0 + wq0 + lr;
    const char* ebase = (const char*)embh;

    // ---- stage tile 0 -> LDS buf0; prefetch tile 1 to regs ----
    uint4 st[8];
    #pragma unroll
    for (int k = 0; k < 8; ++k)
        st[k] = *(const uint4*)(ebase + (size_t)(t + k*128) * 16);
    #pragma unroll
    for (int k = 0; k < 8; ++k) {
        const int idx = t + k*128;
        *(uint4*)(smem + (idx >> 5)*CROWB + (idx & 31)*16) = st[k];
    }
    #pragma unroll
    for (int k = 0; k < 8; ++k)
        st[k] = *(const uint4*)(ebase + 16384 + (size_t)(t + k*128) * 16);
    float es_cur = esq_g[lr];
    float es_nxt = esq_g[32 + lr];

    // ---- A fragments (16 x bf16x8): lane = query lr, k-half = half; 2-deep pipelined ----
    bf16x8 A[16];
    float zsq_p = 0.f;
    {
        float v0[8], v1[8];
        #pragma unroll
        for (int j = 0; j < 8; ++j) v0[j] = zb[(size_t)(half*8 + j) * SP];
        #pragma unroll
        for (int ks = 0; ks < 16; ++ks) {
            if (ks < 15) {
                #pragma unroll
                for (int j = 0; j < 8; ++j) v1[j] = zb[(size_t)((ks+1)*16 + half*8 + j) * SP];
            }
            bf16x8 a;
            #pragma unroll
            for (int j = 0; j < 8; ++j) { zsq_p += v0[j]*v0[j]; a[j] = (short)f2bf(v0[j]); }
            A[ks] = a;
            #pragma unroll
            for (int j = 0; j < 8; ++j) v0[j] = v1[j];
        }
    }
    zsq_p += __shfl_xor(zsq_p, 32, 64);
    if (half == 0) zsql[wq0 + lr] = zsq_p;
    __syncthreads();

    unsigned m1[16], m2[16], m3[16];
    #pragma unroll
    for (int s = 0; s < 16; ++s) { m1[s]=0xFFFFFFFFu; m2[s]=0xFFFFFFFFu; m3[s]=0xFFFFFFFFu; }

    int cur = 0;
    for (int it = 0; it < NTILE; ++it) {
        // ---- MFMA on buf[cur]: 2 independent chains over even/odd k ----
        const unsigned char* bb = smem + cur*TILEB + lr*CROWB + half*16;
        f32x16 accA = {0.f,0.f,0.f,0.f,0.f,0.f,0.f,0.f,0.f,0.f,0.f,0.f,0.f,0.f,0.f,0.f};
        f32x16 accB = {0.f,0.f,0.f,0.f,0.f,0.f,0.f,0.f,0.f,0.f,0.f,0.f,0.f,0.f,0.f,0.f};
        #pragma unroll
        for (int ks = 0; ks < 8; ++ks) {
            const bf16x8 B0 = *(const bf16x8*)(bb + (2*ks)*32);
            const bf16x8 B1 = *(const bf16x8*)(bb + (2*ks+1)*32);
            accA = __builtin_amdgcn_mfma_f32_32x32x16_bf16(A[2*ks],   B0, accA, 0, 0, 0);
            accB = __builtin_amdgcn_mfma_f32_32x32x16_bf16(A[2*ks+1], B1, accB, 0, 0, 0);
        }
        // ---- fold top-3 (biased-positive keys; 8 VALU/score) ----
        const unsigned kc = (unsigned)(it*32 + lr);
        #pragma unroll
        for (int s = 0; s < 16; ++s) {
            const float sc = __builtin_fmaf(-2.0f, accA[s] + accB[s], es_cur);
            const unsigned p = (__float_as_uint(sc) & KEYMASK) | kc;
            const unsigned x = umx(m1[s], p); m1[s] = umn(m1[s], p);
            const unsigned y = umx(m2[s], x); m2[s] = umn(m2[s], x);
            m3[s] = umn(m3[s], y);
        }
        // ---- write prefetched tile it+1 into other buffer (write late) ----
        if (it + 1 < NTILE) {
            #pragma unroll
            for (int k = 0; k < 8; ++k) {
                const int idx = t + k*128;
                *(uint4*)(smem + (cur^1)*TILEB + (idx >> 5)*CROWB + (idx & 31)*16) = st[k];
            }
            es_cur = es_nxt;
        }
        // ---- issue loads for tile it+2 (issue early; a full iter of cover) ----
        if (it + 2 < NTILE) {
            #pragma unroll
            for (int k = 0; k < 8; ++k)
                st[k] = *(const uint4*)(ebase + (size_t)(it+2)*16384 + (size_t)(t + k*128)*16);
            es_nxt = esq_g[(it+2)*32 + lr];
        }
        __syncthreads();           // single barrier: reads(cur) done & writes(cur^1) visible
        cur ^= 1;
    }

    // ---- butterfly across 32 lanes (per half): top-3/lane -> exact top-4/query ----
    #pragma unroll
    for (int s = 0; s < 16; ++s) {
        unsigned t1 = m1[s], t2 = m2[s], t3 = m3[s], t4 = 0xFFFFFFFFu;
        #pragma unroll
        for (int m = 1; m < 32; m <<= 1) {
            const unsigned b1 = (unsigned)__shfl_xor((int)t1, m, 64);
            const unsigned b2 = (unsigned)__shfl_xor((int)t2, m, 64);
            const unsigned b3 = (unsigned)__shfl_xor((int)t3, m, 64);
            const unsigned b4 = (unsigned)__shfl_xor((int)t4, m, 64);
            #define INS(v) { unsigned x_=umx(t1,(v)); t1=umn(t1,(v)); \
                             unsigned y_=umx(t2,x_);  t2=umn(t2,x_);  \
                             unsigned z_=umx(t3,y_);  t3=umn(t3,y_);  \
                             t4=umn(t4,z_); }
            INS(b1); INS(b2); INS(b3); INS(b4);
            #undef INS
        }
        if (lr == s) {
            const int r  = (s & 3) + ((s >> 2) << 3) + (half << 2);
            const int qq = wq0 + r;
            top1[qq] = t1; top2[qq] = t2; top3[qq] = t3; top4[qq] = t4;
        }
    }
    __syncthreads();

    // ---- finalize: idx, ambiguity enqueue, loss (wave 0) ----
    if (t < QT) {
        const unsigned k1 = top1[t], k2 = top2[t], k3 = top3[t], k4 = top4[t];
        const int I1 = (int)(k1 & 1023u);
        fidx[t] = I1;
        out[ZQTOT + 1 + n0 + t] = (float)I1;
        const float s0 = keyval(k1) - BIAS;
        if (keyval(k2) - keyval(k1) < AMB_THR) {
            unsigned pos = atomicAdd(amb_cnt, 1u);
            if (pos < MAX_AMB)
                wl4[pos] = make_uint4((unsigned)(n0 + t),
                                      (k1 & 1023u) | ((k2 & 1023u) << 16),
                                      (k3 & 1023u) | ((k4 & 1023u) << 16), 0u);
        }
        float lq = zsql[t] + s0;         // ||z-e||^2 = zsq + (esq - 2 dot)
        #pragma unroll
        for (int off = 32; off > 0; off >>= 1) lq += __shfl_down(lq, off, 64);
        if (t == 0)
            atomicAdd(loss_acc, (unsigned long long)(long long)((double)lq * LOSS_SCALE));
    }
    __syncthreads();

    // ---- z_q write: stream emb[fidx] rows (STE output == e, tol 20.48) ----
    {
        const int q  = t & 63;
        const int dh = t >> 6;           // wave w writes dims [128w, 128w+128)
        const int fq = fidx[q];
        const float4* ev = (const float4*)(emb + (size_t)fq * CDIM + dh * 128);
        float* ob = out + (size_t)b * BSTRIDE + (size_t)dh * 128 * SP + sp0 + q;
        #pragma unroll
        for (int i = 0; i < 32; ++i) {
            const float4 v = ev[i];
            float* o = ob + (size_t)(i * 4) * SP;
            o[0]            = v.x;
            o[SP]           = v.y;
            o[2*SP]         = v.z;
            o[(size_t)3*SP] = v.w;
        }
    }
}

// ---------------- fixup: wave-parallel np-exact, grid-stride over worklist ----------------
__global__ __launch_bounds__(64)
void vq_fix_cand(const float* __restrict__ z, const float* __restrict__ emb,
                 float* __restrict__ out, const unsigned int* __restrict__ amb_cnt,
                 const uint4* __restrict__ wl4) {
    __shared__ float zrow[CDIM];
    __shared__ float erow[4][CDIM];
    __shared__ float dsh[4], esh[4];
    __shared__ float zss;

    unsigned cnt = *amb_cnt; if (cnt > MAX_AMB) cnt = MAX_AMB;
    const int l = threadIdx.x;

    for (unsigned widx = blockIdx.x; widx < cnt; widx += gridDim.x) {
        __syncthreads();    // protect LDS reuse across iterations
        const uint4 e = wl4[widx];
        const int n = (int)e.x;
        const int b = n >> 14, sp = n & 16383;
        int codes[4] = { (int)(e.y & 1023u), (int)((e.y >> 16) & 1023u),
                         (int)(e.z & 1023u), (int)((e.z >> 16) & 1023u) };

        #pragma unroll
        for (int i = 0; i < 4; ++i) {
            const int c = l + 64*i;
            zrow[c] = z[(size_t)b * BSTRIDE + (size_t)c * SP + sp];
        }
        {
            const int r = l >> 4, c0 = (l & 15) * 16;
            const float4* src = (const float4*)(emb + (size_t)codes[r] * CDIM + c0);
            float4* dst = (float4*)&erow[r][c0];
            #pragma unroll
            for (int i = 0; i < 4; ++i) dst[i] = src[i];
        }
        __syncthreads();

        const int role = l >> 4, rr = (l >> 2) & 3, a = l & 3;
        if (role == 0) {
            // np.einsum dots: lane (rr,a) runs the mod-4 accumulator 'a' for candidate rr
            const float* er = erow[rr];
            float acc = __fmul_rn(zrow[a], er[a]);
            for (int i = 1; i < 64; ++i)
                acc = __fadd_rn(acc, __fmul_rn(zrow[4*i + a], er[4*i + a]));
            const float u = __fadd_rn(acc, __shfl_xor(acc, 1, 64));
            const float d = __fadd_rn(u,   __shfl_xor(u,   2, 64));  // (a0+a1)+(a2+a3)
            if (a == 0) dsh[rr] = d;
        } else if (role == 1 || (role == 2 && rr == 0)) {
            // np pairwise_sum of squares: chains j=a, j=a+4, both 128-halves
            const float* src = (role == 1) ? erow[rr] : zrow;
            float pA = __fmul_rn(src[a],       src[a]);
            float pB = __fmul_rn(src[a+4],     src[a+4]);
            float qA = __fmul_rn(src[128+a],   src[128+a]);
            float qB = __fmul_rn(src[128+a+4], src[128+a+4]);
            #pragma unroll 4
            for (int i = 1; i < 16; ++i) {
                pA = __fadd_rn(pA, __fmul_rn(src[8*i+a],       src[8*i+a]));
                pB = __fadd_rn(pB, __fmul_rn(src[8*i+a+4],     src[8*i+a+4]));
                qA = __fadd_rn(qA, __fmul_rn(src[128+8*i+a],   src[128+8*i+a]));
                qB = __fadd_rn(qB, __fmul_rn(src[128+8*i+a+4], src[128+8*i+a+4]));
            }
            float uA = __fadd_rn(pA, __shfl_xor(pA, 1, 64));
            float vA = __fadd_rn(uA, __shfl_xor(uA, 2, 64));   // (r0+r1)+(r2+r3)
            float uB = __fadd_rn(pB, __shfl_xor(pB, 1, 64));
            float vB = __fadd_rn(uB, __shfl_xor(uB, 2, 64));   // (r4+r5)+(r6+r7)
            const float h0 = __fadd_rn(vA, vB);                // pw128 half0
            float uC = __fadd_rn(qA, __shfl_xor(qA, 1, 64));
            float vC = __fadd_rn(uC, __shfl_xor(uC, 2, 64));
            float uD = __fadd_rn(qB, __shfl_xor(qB, 1, 64));
            float vD = __fadd_rn(uD, __shfl_xor(uD, 2, 64));
            const float h1 = __fadd_rn(vC, vD);                // pw128 half1
            const float stot = __fadd_rn(h0, h1);
            if (a == 0) { if (role == 1) esh[rr] = stot; else zss = stot; }
        }
        __syncthreads();
        if (l == 0) {
            float bd = 3.4e38f; int bk = KCODES;
            #pragma unroll
            for (int i = 0; i < 4; ++i) {
                const float d = __fsub_rn(__fadd_rn(zss, esh[i]), __fmul_rn(2.0f, dsh[i]));
                if (d < bd || (d == bd && codes[i] < bk)) { bd = d; bk = codes[i]; }
            }
            out[ZQTOT + 1 + n] = (float)bk;   // np.argmin first-index semantics
        }
    }
}

// ---------------- fallback (round-3 proven path, used if ws too small) ----------------
__global__ __launch_bounds__(256)
void vq_main_basic(const float* __restrict__ z, const float* __restrict__ emb,
                   float* __restrict__ out, unsigned long long* __restrict__ loss_acc,
                   unsigned int* __restrict__ amb_cnt, unsigned int* __restrict__ wl) {
    __shared__ float zlz[64 * CDIM];
    __shared__ float esq[KCODES];
    __shared__ float m1s[4][64], m2s[4][64];
    __shared__ int   i1s[4][64];
    __shared__ int   fidx[64];
    __shared__ float lsum[4];

    const int t  = threadIdx.x;
    const int q  = t & 63;
    const int w  = __builtin_amdgcn_readfirstlane(t >> 6);
    const int qs = q & 7;
    const int n0 = blockIdx.x * 64;
    const int b  = n0 >> 14;
    const int sp0 = n0 & 16383;
    const float* zb = z + (size_t)b * BSTRIDE;

    #pragma unroll 4
    for (int i = 0; i < 64; ++i) {
        int c = (t >> 6) * 64 + i;
        float v = zb[(size_t)c * SP + sp0 + q];
        zlz[q * CDIM + ((((c >> 2) ^ qs) << 2) | (c & 3))] = v;
    }
    for (int k = t; k < KCODES; k += 256) {
        const float4* er = (const float4*)(emb + (size_t)k * CDIM);
        float s = 0.f;
        for (int c4 = 0; c4 < 64; ++c4) {
            float4 e = er[c4];
            s += e.x*e.x + e.y*e.y + e.z*e.z + e.w*e.w;
        }
        esq[k] = s;
    }
    __syncthreads();

    float m1 = 3.4e38f, m2 = 3.4e38f; int i1 = 0;
    const float* zrow = zlz + q * CDIM;
    const int kbase = w * 256;
    for (int kk = 0; kk < 256; kk += 8) {
        const int k0 = kbase + kk;
        float acc[8] = {0,0,0,0,0,0,0,0};
        for (int c4 = 0; c4 < 64; ++c4) {
            float4 zv = *(const float4*)(zrow + ((c4 ^ qs) << 2));
            #pragma unroll
            for (int j = 0; j < 8; ++j) {
                float4 ev = *(const float4*)(emb + (size_t)(k0 + j) * CDIM + (c4 << 2));
                acc[j] += zv.x*ev.x + zv.y*ev.y + zv.z*ev.z + zv.w*ev.w;
            }
        }
        #pragma unroll
        for (int j = 0; j < 8; ++j) {
            float s = esq[k0 + j] - 2.0f * acc[j];
            if (s < m1)      { m2 = m1; m1 = s; i1 = k0 + j; }
            else if (s < m2) { m2 = s; }
        }
    }
    m1s[w][q] = m1; m2s[w][q] = m2; i1s[w][q] = i1;
    __syncthreads();

    if (t < 64) {
        float M1 = 3.4e38f, M2 = 3.4e38f; int I1 = 0;
        for (int g = 0; g < 4; ++g) {
            float v1 = m1s[g][t], v2 = m2s[g][t];
            int   a1 = i1s[g][t];
            if (v1 < M1) { M2 = M1; M1 = v1; I1 = a1; }
            else if (v1 < M2) { M2 = v1; }
            if (v2 < M2) { M2 = v2; }
        }
        if (M2 - M1 < 1.5e-4f) {
            unsigned pos = atomicAdd(amb_cnt, 1u);
            if (pos < MAX_AMB) wl[pos] = n0 + t;
        }
        fidx[t] = I1;
        out[ZQTOT + 1 + n0 + t] = (float)I1;
    }
    __syncthreads();

    const int fq = fidx[q];
    const float* eq = emb + (size_t)fq * CDIM;
    float ls = 0.f;
    #pragma unroll 4
    for (int i = 0; i < 64; ++i) {
        int c = (t >> 6) * 64 + i;
        float zv = zrow[((((c >> 2) ^ qs) << 2) | (c & 3))];
        float ev = eq[c];
        float d = ev - zv;
        ls += d * d;
        out[(size_t)b * BSTRIDE + (size_t)c * SP + sp0 + q] = zv + d;
    }
    #pragma unroll
    for (int off = 32; off > 0; off >>= 1) ls += __shfl_down(ls, off, 64);
    if (q == 0) lsum[w] = ls;
    __syncthreads();
    if (t == 0) {
        float tot = lsum[0] + lsum[1] + lsum[2] + lsum[3];
        atomicAdd(loss_acc, (unsigned long long)(long long)((double)tot * LOSS_SCALE));
    }
}

__global__ __launch_bounds__(256)
void vq_fix_np(const float* __restrict__ z, const float* __restrict__ emb,
               float* __restrict__ out, const unsigned int* __restrict__ amb_cnt,
               const unsigned int* __restrict__ wl) {
    __shared__ float zrow[CDIM];
    __shared__ float zsq_sh;
    __shared__ float rd[256];
    __shared__ int   rk[256];

    unsigned cnt = *amb_cnt; if (cnt > MAX_AMB) cnt = MAX_AMB;
    if (blockIdx.x >= cnt) return;
    const int n = (int)wl[blockIdx.x];
    const int b = n >> 14, sp = n & 16383;
    const int t = threadIdx.x;

    zrow[t] = z[(size_t)b * BSTRIDE + (size_t)t * SP + sp];
    __syncthreads();
    if (t == 0) zsq_sh = pairwise256_sq(zrow);
    __syncthreads();
    const float zsq = zsq_sh;

    float bestd = 3.4e38f; int bestk = KCODES;
    for (int j = 0; j < 4; ++j) {
        const int k = t + 256 * j;
        const float* er = emb + (size_t)k * CDIM;
        const float dot = np_dot256(zrow, er);
        const float es  = pairwise256_sq(er);
        const float d   = __fsub_rn(__fadd_rn(zsq, es), __fmul_rn(2.0f, dot));
        if (d < bestd || (d == bestd && k < bestk)) { bestd = d; bestk = k; }
    }
    rd[t] = bestd; rk[t] = bestk;
    __syncthreads();
    for (int s = 128; s > 0; s >>= 1) {
        if (t < s) {
            float od = rd[t + s]; int ok = rk[t + s];
            if (od < rd[t] || (od == rd[t] && ok < rk[t])) { rd[t] = od; rk[t] = ok; }
        }
        __syncthreads();
    }
    if (t == 0) out[ZQTOT + 1 + n] = (float)rk[0];
}

__global__ void vq_final(const unsigned long long* __restrict__ acc, float* __restrict__ out) {
    if (threadIdx.x == 0 && blockIdx.x == 0) {
        double mse = (double)(long long)acc[0] / LOSS_SCALE / (double)ZQTOT;
        out[ZQTOT] = (float)(mse * 1.25);   // (1 + beta) * mse
    }
}

extern "C" void kernel_launch(void* const* d_in, const int* in_sizes, int n_in,
                              void* d_out, int out_size, void* d_ws, size_t ws_size,
                              hipStream_t stream) {
    const float* z   = (const float*)d_in[0];
    const float* emb = (const float*)d_in[1];
    float* out = (float*)d_out;

    unsigned long long* loss_acc = (unsigned long long*)d_ws;
    unsigned int* amb_cnt = (unsigned int*)((char*)d_ws + 8);
    const size_t WL4_OFF  = 64;
    const size_t ESQ_OFF  = (WL4_OFF + (size_t)MAX_AMB * 16 + 255) & ~(size_t)255;
    const size_t EMBH_OFF = (ESQ_OFF + (size_t)KCODES * 4 + 255) & ~(size_t)255;
    const size_t WS_NEED  = EMBH_OFF + (size_t)KCODES * CDIM * 2;

    hipMemsetAsync(d_ws, 0, 16, stream);
    if (ws_size >= WS_NEED) {
        uint4* wl4 = (uint4*)((char*)d_ws + WL4_OFF);
        float* esq_g = (float*)((char*)d_ws + ESQ_OFF);
        unsigned short* embh = (unsigned short*)((char*)d_ws + EMBH_OFF);
        vq_prep<<<dim3(KCODES), dim3(64), 0, stream>>>(emb, embh, esq_g);
        vq_main_mfma<<<dim3(NQ / QT), dim3(128), 0, stream>>>(z, emb, embh, esq_g,
                                                              out, loss_acc, amb_cnt, wl4);
        vq_fix_cand<<<dim3(2048), dim3(64), 0, stream>>>(z, emb, out, amb_cnt, wl4);
    } else {
        unsigned int* wl = (unsigned int*)((char*)d_ws + WL4_OFF);
        vq_main_basic<<<dim3(NQ / 64), dim3(256), 0, stream>>>(z, emb, out, loss_acc, amb_cnt, wl);
        vq_fix_np<<<dim3(MAX_AMB), dim3(256), 0, stream>>>(z, emb, out, amb_cnt, wl);
    }
    vq_final<<<dim3(1), dim3(64), 0, stream>>>(loss_acc, out);
}

// Round 10
// 177.545 us; speedup vs baseline: 1.2472x; 1.1852x over previous
//
#include <hip/hip_runtime.h>

#define KCODES 1024
#define CDIM   256
#define SP     16384           // D*H*W
#define ZQTOT  16777216        // B*C*D*H*W
#define NQ     65536           // B*D*H*W
#define BSTRIDE 4194304        // C*SP
#define MAX_AMB 12288
#define LOSS_SCALE 33554432.0  // 2^25 fixed-point deterministic loss
#define KEYMASK 0xFFFFFC00u
#define AMB_THR 6.0e-4f

#define QT2    128             // queries per block (main kernel)
#define NTILE  32              // 32 code-tiles of 32 codes
#define ROWB   528             // padded LDS bytes per code row (33*16)
#define TILEB  16896           // 32*528

using f32x4  = __attribute__((ext_vector_type(4)))  float;
using f32x16 = __attribute__((ext_vector_type(16))) float;
using bf16x8 = __attribute__((ext_vector_type(8)))  short;

__device__ __forceinline__ unsigned short f2bf(float x) {   // RNE f32->bf16
    unsigned u = __float_as_uint(x);
    u += 0x7fffu + ((u >> 16) & 1u);
    return (unsigned short)(u >> 16);
}
__device__ __forceinline__ unsigned fkey(float s) {         // monotone f32->u32
    unsigned u = __float_as_uint(s);
    return u ^ ((unsigned)((int)u >> 31) | 0x80000000u);
}
__device__ __forceinline__ float funkey(unsigned k) {
    return (k & 0x80000000u) ? __uint_as_float(k ^ 0x80000000u)
                             : __uint_as_float(~k);
}
__device__ __forceinline__ unsigned umn(unsigned a, unsigned b){ return a < b ? a : b; }
__device__ __forceinline__ unsigned umx(unsigned a, unsigned b){ return a > b ? a : b; }

// ---- numpy pairwise_sum replication (base case n=128, 8 accumulators) ----
__device__ __forceinline__ float pw128_sq(const float* a) {
    float r[8];
    #pragma unroll
    for (int j = 0; j < 8; ++j) r[j] = __fmul_rn(a[j], a[j]);
    for (int i = 8; i < 128; i += 8) {
        #pragma unroll
        for (int j = 0; j < 8; ++j) r[j] = __fadd_rn(r[j], __fmul_rn(a[i+j], a[i+j]));
    }
    return __fadd_rn(__fadd_rn(__fadd_rn(r[0], r[1]), __fadd_rn(r[2], r[3])),
                     __fadd_rn(__fadd_rn(r[4], r[5]), __fadd_rn(r[6], r[7])));
}
__device__ __forceinline__ float pairwise256_sq(const float* a) {
    return __fadd_rn(pw128_sq(a), pw128_sq(a + 128));
}
// np.einsum SSE path: 4 mod-4 accumulators, separate mul/add roundings
__device__ __forceinline__ float np_dot256(const float* zr, const float* er) {
    float a0 = 0.f, a1 = 0.f, a2 = 0.f, a3 = 0.f;
    for (int i8 = 0; i8 < 256; i8 += 8) {
        a0 = __fadd_rn(a0, __fmul_rn(zr[i8+0], er[i8+0]));
        a1 = __fadd_rn(a1, __fmul_rn(zr[i8+1], er[i8+1]));
        a2 = __fadd_rn(a2, __fmul_rn(zr[i8+2], er[i8+2]));
        a3 = __fadd_rn(a3, __fmul_rn(zr[i8+3], er[i8+3]));
        a0 = __fadd_rn(a0, __fmul_rn(zr[i8+4], er[i8+4]));
        a1 = __fadd_rn(a1, __fmul_rn(zr[i8+5], er[i8+5]));
        a2 = __fadd_rn(a2, __fmul_rn(zr[i8+6], er[i8+6]));
        a3 = __fadd_rn(a3, __fmul_rn(zr[i8+7], er[i8+7]));
    }
    return __fadd_rn(__fadd_rn(a0, a1), __fadd_rn(a2, a3));
}

// ---------------- pre-pass: emb -> bf16 (hi only) + esq ----------------
__global__ __launch_bounds__(64)
void vq_prep(const float* __restrict__ emb, unsigned short* __restrict__ embh,
             float* __restrict__ esq_g) {
    const int k = blockIdx.x;
    const int l = threadIdx.x;
    float4 v = ((const float4*)(emb + (size_t)k * CDIM))[l];
    float s = v.x*v.x + v.y*v.y + v.z*v.z + v.w*v.w;
    unsigned short h0=f2bf(v.x), h1=f2bf(v.y), h2=f2bf(v.z), h3=f2bf(v.w);
    uint2 hh; hh.x = (unsigned)h0 | ((unsigned)h1<<16); hh.y = (unsigned)h2 | ((unsigned)h3<<16);
    *(uint2*)&embh[(size_t)k*CDIM + l*4] = hh;
    #pragma unroll
    for (int off = 32; off > 0; off >>= 1) s += __shfl_down(s, off, 64);
    if (l == 0) esq_g[k] = s;
}

// ---------------- MFMA main kernel: r7 structure + XCD-bijective swizzle ----------------
__global__ __launch_bounds__(256, 2)
void vq_main_mfma(const float* __restrict__ z, const float* __restrict__ emb,
                  const unsigned short* __restrict__ embh,
                  const float* __restrict__ esq_g,
                  float* __restrict__ out, unsigned long long* __restrict__ loss_acc,
                  unsigned int* __restrict__ amb_cnt, uint4* __restrict__ wl4) {
    __shared__ __align__(16) unsigned char smem[2*TILEB + 4096];
    unsigned* top1 = (unsigned*)(smem + 2*TILEB);          // 128 u32
    unsigned* top2 = top1 + 128;
    unsigned* top3 = top2 + 128;
    float*    zsql = (float*)(top3 + 128);                 // 128 f32
    int*      fidx = (int*)(zsql + 128);                   // 128 i32
    float*    lpart = (float*)(fidx + 128);                // 2 f32

    const int t    = threadIdx.x;
    const int l    = t & 63;
    const int w    = t >> 6;
    const int half = l >> 5;
    const int lr   = l & 31;
    // XCD-bijective swizzle (nwg=512, 512%8==0): blocks resident on one XCD
    // cover 64 consecutive spatial tiles -> L2-aggregated 256B chunks.
    const int bid  = blockIdx.x;
    const int obid = ((bid & 7) << 6) + (bid >> 3);
    const int n0   = obid * QT2;
    const int b    = n0 >> 14;
    const int sp0  = n0 & 16383;
    const int wq0  = w * 32;
    const float* zb = z + (size_t)b * BSTRIDE + sp0 + wq0 + lr;

    // ---- issue tile-0 B stage loads (latency covered by A-load below) ----
    uint4 st[4];
    const char* ebase = (const char*)embh;
    #pragma unroll
    for (int k = 0; k < 4; ++k)
        st[k] = *(const uint4*)(ebase + (size_t)(t + k*256) * 16);

    // ---- A fragments in registers: lane = query (lr), k-half (half) ----
    bf16x8 A[16];
    float zsq_p = 0.f;
    #pragma unroll
    for (int ks = 0; ks < 16; ++ks) {
        const float* zp = zb + (size_t)(ks*16 + half*8) * SP;
        float v[8];
        #pragma unroll
        for (int j = 0; j < 8; ++j) v[j] = zp[(size_t)j * SP];
        bf16x8 a;
        #pragma unroll
        for (int j = 0; j < 8; ++j) {
            zsq_p += v[j] * v[j];
            a[j] = (short)f2bf(v[j]);
        }
        A[ks] = a;
    }
    zsq_p += __shfl_xor(zsq_p, 32, 64);
    if (half == 0) zsql[wq0 + lr] = zsq_p;

    // ---- write tile 0 into LDS buffer 0 (padded rows) ----
    #pragma unroll
    for (int k = 0; k < 4; ++k) {
        const int idx = t + k*256;
        *(uint4*)(smem + (idx >> 5)*ROWB + (idx & 31)*16) = st[k];
    }
    __syncthreads();

    unsigned m1v[16], m2v[16], m3v[16];
    #pragma unroll
    for (int s = 0; s < 16; ++s) { m1v[s]=0xFFFFFFFFu; m2v[s]=0xFFFFFFFFu; m3v[s]=0xFFFFFFFFu; }

    int cur = 0;
    for (int tile = 0; tile < NTILE; ++tile) {
        // prefetch next tile's B into registers (issue early: full MFMA phase covers)
        if (tile + 1 < NTILE) {
            #pragma unroll
            for (int k = 0; k < 4; ++k)
                st[k] = *(const uint4*)(ebase + (size_t)(tile+1)*16384 + (size_t)(t + k*256)*16);
        }
        const float es = esq_g[tile*32 + lr];

        const unsigned char* bb = smem + cur*TILEB + lr*ROWB + half*16;
        f32x16 acc = {0.f,0.f,0.f,0.f,0.f,0.f,0.f,0.f,0.f,0.f,0.f,0.f,0.f,0.f,0.f,0.f};
        #pragma unroll
        for (int ks = 0; ks < 16; ++ks) {
            const bf16x8 Bv = *(const bf16x8*)(bb + ks*32);
            acc = __builtin_amdgcn_mfma_f32_32x32x16_bf16(A[ks], Bv, acc, 0, 0, 0);
        }
        // fold: lane's code = tile*32+lr; reg s = query row (s&3)+8*(s>>2)+4*half
        const unsigned kc = (unsigned)(tile*32 + lr);
        #pragma unroll
        for (int s = 0; s < 16; ++s) {
            const float sc = __builtin_fmaf(-2.0f, acc[s], es);
            const unsigned p = (fkey(sc) & KEYMASK) | kc;
            const unsigned x = umx(m1v[s], p); m1v[s] = umn(m1v[s], p);
            const unsigned y = umx(m2v[s], x); m2v[s] = umn(m2v[s], x);
            m3v[s] = umn(m3v[s], y);
        }
        __syncthreads();                 // all reads of buffers done
        if (tile + 1 < NTILE) {          // write next tile (write late)
            #pragma unroll
            for (int k = 0; k < 4; ++k) {
                const int idx = t + k*256;
                *(uint4*)(smem + (cur^1)*TILEB + (idx >> 5)*ROWB + (idx & 31)*16) = st[k];
            }
        }
        __syncthreads();
        cur ^= 1;
    }

    // ---- butterfly merge of top-3 across the 32 lanes of each half-wave ----
    #pragma unroll
    for (int s = 0; s < 16; ++s) {
        unsigned a1 = m1v[s], a2 = m2v[s], a3 = m3v[s];
        #pragma unroll
        for (int m = 1; m < 32; m <<= 1) {
            const unsigned b1 = (unsigned)__shfl_xor((int)a1, m, 64);
            const unsigned b2 = (unsigned)__shfl_xor((int)a2, m, 64);
            const unsigned b3 = (unsigned)__shfl_xor((int)a3, m, 64);
            const unsigned hi1 = umx(a1, b1), lo2 = umn(a2, b2);
            const unsigned r3  = umn(umx(hi1, lo2), umn(a3, b3));
            a1 = umn(a1, b1);
            a2 = umn(hi1, lo2);
            a3 = r3;
        }
        if (lr == s) {
            const int r = (s & 3) + ((s >> 2) << 3) + (half << 2);
            top1[wq0 + r] = a1; top2[wq0 + r] = a2; top3[wq0 + r] = a3;
        }
    }
    __syncthreads();

    // ---- per-query finalize: idx, ambiguity enqueue, loss ----
    if (t < QT2) {
        const unsigned k1 = top1[t], k2 = top2[t], k3 = top3[t];
        const int I1 = (int)(k1 & 1023u);
        fidx[t] = I1;
        out[ZQTOT + 1 + n0 + t] = (float)I1;
        const float s0 = funkey(k1 & KEYMASK);
        if (funkey(k2 & KEYMASK) - s0 < AMB_THR) {
            unsigned pos = atomicAdd(amb_cnt, 1u);
            if (pos < MAX_AMB)
                wl4[pos] = make_uint4((unsigned)(n0 + t),
                                      (k1 & 1023u) | ((k2 & 1023u) << 16),
                                      (k3 & 1023u) | ((k3 & 1023u) << 16), 0u);
        }
        float lq = zsql[t] + s0;         // ||z-e||^2 = zsq + (esq - 2 dot)
        #pragma unroll
        for (int off = 32; off > 0; off >>= 1) lq += __shfl_down(lq, off, 64);
        if ((t & 63) == 0) lpart[t >> 6] = lq;
    }
    __syncthreads();
    if (t == 0)
        atomicAdd(loss_acc, (unsigned long long)(long long)((double)(lpart[0] + lpart[1]) * LOSS_SCALE));

    // ---- z_q write: stream emb[fidx] rows (STE output == e, tol 20.48) ----
    {
        const int q  = t & 127;
        const int dh = t >> 7;
        const int fq = fidx[q];
        const float4* ev = (const float4*)(emb + (size_t)fq * CDIM + dh * 128);
        float* ob = out + (size_t)b * BSTRIDE + (size_t)dh * 128 * SP + sp0 + q;
        #pragma unroll
        for (int i = 0; i < 32; ++i) {
            const float4 v = ev[i];
            float* o = ob + (size_t)(i * 4) * SP;
            o[0]            = v.x;
            o[SP]           = v.y;
            o[2*SP]         = v.z;
            o[(size_t)3*SP] = v.w;
        }
    }
}

// ---------------- fixup: wave-parallel np-exact, grid-stride over worklist ----------------
__global__ __launch_bounds__(64)
void vq_fix_cand(const float* __restrict__ z, const float* __restrict__ emb,
                 float* __restrict__ out, const unsigned int* __restrict__ amb_cnt,
                 const uint4* __restrict__ wl4) {
    __shared__ float zrow[CDIM];
    __shared__ float erow[4][CDIM];
    __shared__ float dsh[4], esh[4];
    __shared__ float zss;

    unsigned cnt = *amb_cnt; if (cnt > MAX_AMB) cnt = MAX_AMB;
    const int l = threadIdx.x;

    for (unsigned widx = blockIdx.x; widx < cnt; widx += gridDim.x) {
        __syncthreads();    // protect LDS reuse across iterations
        const uint4 e = wl4[widx];
        const int n = (int)e.x;
        const int b = n >> 14, sp = n & 16383;
        int codes[4] = { (int)(e.y & 1023u), (int)((e.y >> 16) & 1023u),
                         (int)(e.z & 1023u), (int)((e.z >> 16) & 1023u) };

        #pragma unroll
        for (int i = 0; i < 4; ++i) {
            const int c = l + 64*i;
            zrow[c] = z[(size_t)b * BSTRIDE + (size_t)c * SP + sp];
        }
        {
            const int r = l >> 4, c0 = (l & 15) * 16;
            const float4* src = (const float4*)(emb + (size_t)codes[r] * CDIM + c0);
            float4* dst = (float4*)&erow[r][c0];
            #pragma unroll
            for (int i = 0; i < 4; ++i) dst[i] = src[i];
        }
        __syncthreads();

        const int role = l >> 4, rr = (l >> 2) & 3, a = l & 3;
        if (role == 0) {
            // np.einsum dots: lane (rr,a) runs the mod-4 accumulator 'a' for candidate rr
            const float* er = erow[rr];
            float acc = __fmul_rn(zrow[a], er[a]);
            for (int i = 1; i < 64; ++i)
                acc = __fadd_rn(acc, __fmul_rn(zrow[4*i + a], er[4*i + a]));
            const float u = __fadd_rn(acc, __shfl_xor(acc, 1, 64));
            const float d = __fadd_rn(u,   __shfl_xor(u,   2, 64));  // (a0+a1)+(a2+a3)
            if (a == 0) dsh[rr] = d;
        } else if (role == 1 || (role == 2 && rr == 0)) {
            // np pairwise_sum of squares: chains j=a, j=a+4, both 128-halves
            const float* src = (role == 1) ? erow[rr] : zrow;
            float pA = __fmul_rn(src[a],       src[a]);
            float pB = __fmul_rn(src[a+4],     src[a+4]);
            float qA = __fmul_rn(src[128+a],   src[128+a]);
            float qB = __fmul_rn(src[128+a+4], src[128+a+4]);
            #pragma unroll 4
            for (int i = 1; i < 16; ++i) {
                pA = __fadd_rn(pA, __fmul_rn(src[8*i+a],       src[8*i+a]));
                pB = __fadd_rn(pB, __fmul_rn(src[8*i+a+4],     src[8*i+a+4]));
                qA = __fadd_rn(qA, __fmul_rn(src[128+8*i+a],   src[128+8*i+a]));
                qB = __fadd_rn(qB, __fmul_rn(src[128+8*i+a+4], src[128+8*i+a+4]));
            }
            float uA = __fadd_rn(pA, __shfl_xor(pA, 1, 64));
            float vA = __fadd_rn(uA, __shfl_xor(uA, 2, 64));   // (r0+r1)+(r2+r3)
            float uB = __fadd_rn(pB, __shfl_xor(pB, 1, 64));
            float vB = __fadd_rn(uB, __shfl_xor(uB, 2, 64));   // (r4+r5)+(r6+r7)
            const float h0 = __fadd_rn(vA, vB);                // pw128 half0
            float uC = __fadd_rn(qA, __shfl_xor(qA, 1, 64));
            float vC = __fadd_rn(uC, __shfl_xor(uC, 2, 64));
            float uD = __fadd_rn(qB, __shfl_xor(qB, 1, 64));
            float vD = __fadd_rn(uD, __shfl_xor(uD, 2, 64));
            const float h1 = __fadd_rn(vC, vD);                // pw128 half1
            const float stot = __fadd_rn(h0, h1);
            if (a == 0) { if (role == 1) esh[rr] = stot; else zss = stot; }
        }
        __syncthreads();
        if (l == 0) {
            float bd = 3.4e38f; int bk = KCODES;
            #pragma unroll
            for (int i = 0; i < 4; ++i) {
                const float d = __fsub_rn(__fadd_rn(zss, esh[i]), __fmul_rn(2.0f, dsh[i]));
                if (d < bd || (d == bd && codes[i] < bk)) { bd = d; bk = codes[i]; }
            }
            out[ZQTOT + 1 + n] = (float)bk;   // np.argmin first-index semantics
        }
    }
}

// ---------------- fallback (round-3 proven path, used if ws too small) ----------------
__global__ __launch_bounds__(256)
void vq_main_basic(const float* __restrict__ z, const float* __restrict__ emb,
                   float* __restrict__ out, unsigned long long* __restrict__ loss_acc,
                   unsigned int* __restrict__ amb_cnt, unsigned int* __restrict__ wl) {
    __shared__ float zlz[64 * CDIM];
    __shared__ float esq[KCODES];
    __shared__ float m1s[4][64], m2s[4][64];
    __shared__ int   i1s[4][64];
    __shared__ int   fidx[64];
    __shared__ float lsum[4];

    const int t  = threadIdx.x;
    const int q  = t & 63;
    const int w  = __builtin_amdgcn_readfirstlane(t >> 6);
    const int qs = q & 7;
    const int n0 = blockIdx.x * 64;
    const int b  = n0 >> 14;
    const int sp0 = n0 & 16383;
    const float* zb = z + (size_t)b * BSTRIDE;

    #pragma unroll 4
    for (int i = 0; i < 64; ++i) {
        int c = (t >> 6) * 64 + i;
        float v = zb[(size_t)c * SP + sp0 + q];
        zlz[q * CDIM + ((((c >> 2) ^ qs) << 2) | (c & 3))] = v;
    }
    for (int k = t; k < KCODES; k += 256) {
        const float4* er = (const float4*)(emb + (size_t)k * CDIM);
        float s = 0.f;
        for (int c4 = 0; c4 < 64; ++c4) {
            float4 e = er[c4];
            s += e.x*e.x + e.y*e.y + e.z*e.z + e.w*e.w;
        }
        esq[k] = s;
    }
    __syncthreads();

    float m1 = 3.4e38f, m2 = 3.4e38f; int i1 = 0;
    const float* zrow = zlz + q * CDIM;
    const int kbase = w * 256;
    for (int kk = 0; kk < 256; kk += 8) {
        const int k0 = kbase + kk;
        float acc[8] = {0,0,0,0,0,0,0,0};
        for (int c4 = 0; c4 < 64; ++c4) {
            float4 zv = *(const float4*)(zrow + ((c4 ^ qs) << 2));
            #pragma unroll
            for (int j = 0; j < 8; ++j) {
                float4 ev = *(const float4*)(emb + (size_t)(k0 + j) * CDIM + (c4 << 2));
                acc[j] += zv.x*ev.x + zv.y*ev.y + zv.z*ev.z + zv.w*ev.w;
            }
        }
        #pragma unroll
        for (int j = 0; j < 8; ++j) {
            float s = esq[k0 + j] - 2.0f * acc[j];
            if (s < m1)      { m2 = m1; m1 = s; i1 = k0 + j; }
            else if (s < m2) { m2 = s; }
        }
    }
    m1s[w][q] = m1; m2s[w][q] = m2; i1s[w][q] = i1;
    __syncthreads();

    if (t < 64) {
        float M1 = 3.4e38f, M2 = 3.4e38f; int I1 = 0;
        for (int g = 0; g < 4; ++g) {
            float v1 = m1s[g][t], v2 = m2s[g][t];
            int   a1 = i1s[g][t];
            if (v1 < M1) { M2 = M1; M1 = v1; I1 = a1; }
            else if (v1 < M2) { M2 = v1; }
            if (v2 < M2) { M2 = v2; }
        }
        if (M2 - M1 < 1.5e-4f) {
            unsigned pos = atomicAdd(amb_cnt, 1u);
            if (pos < MAX_AMB) wl[pos] = n0 + t;
        }
        fidx[t] = I1;
        out[ZQTOT + 1 + n0 + t] = (float)I1;
    }
    __syncthreads();

    const int fq = fidx[q];
    const float* eq = emb + (size_t)fq * CDIM;
    float ls = 0.f;
    #pragma unroll 4
    for (int i = 0; i < 64; ++i) {
        int c = (t >> 6) * 64 + i;
        float zv = zrow[((((c >> 2) ^ qs) << 2) | (c & 3))];
        float ev = eq[c];
        float d = ev - zv;
        ls += d * d;
        out[(size_t)b * BSTRIDE + (size_t)c * SP + sp0 + q] = zv + d;
    }
    #pragma unroll
    for (int off = 32; off > 0; off >>= 1) ls += __shfl_down(ls, off, 64);
    if (q == 0) lsum[w] = ls;
    __syncthreads();
    if (t == 0) {
        float tot = lsum[0] + lsum[1] + lsum[2] + lsum[3];
        atomicAdd(loss_acc, (unsigned long long)(long long)((double)tot * LOSS_SCALE));
    }
}

__global__ __launch_bounds__(256)
void vq_fix_np(const float* __restrict__ z, const float* __restrict__ emb,
               float* __restrict__ out, const unsigned int* __restrict__ amb_cnt,
               const unsigned int* __restrict__ wl) {
    __shared__ float zrow[CDIM];
    __shared__ float zsq_sh;
    __shared__ float rd[256];
    __shared__ int   rk[256];

    unsigned cnt = *amb_cnt; if (cnt > MAX_AMB) cnt = MAX_AMB;
    if (blockIdx.x >= cnt) return;
    const int n = (int)wl[blockIdx.x];
    const int b = n >> 14, sp = n & 16383;
    const int t = threadIdx.x;

    zrow[t] = z[(size_t)b * BSTRIDE + (size_t)t * SP + sp];
    __syncthreads();
    if (t == 0) zsq_sh = pairwise256_sq(zrow);
    __syncthreads();
    const float zsq = zsq_sh;

    float bestd = 3.4e38f; int bestk = KCODES;
    for (int j = 0; j < 4; ++j) {
        const int k = t + 256 * j;
        const float* er = emb + (size_t)k * CDIM;
        const float dot = np_dot256(zrow, er);
        const float es  = pairwise256_sq(er);
        const float d   = __fsub_rn(__fadd_rn(zsq, es), __fmul_rn(2.0f, dot));
        if (d < bestd || (d == bestd && k < bestk)) { bestd = d; bestk = k; }
    }
    rd[t] = bestd; rk[t] = bestk;
    __syncthreads();
    for (int s = 128; s > 0; s >>= 1) {
        if (t < s) {
            float od = rd[t + s]; int ok = rk[t + s];
            if (od < rd[t] || (od == rd[t] && ok < rk[t])) { rd[t] = od; rk[t] = ok; }
        }
        __syncthreads();
    }
    if (t == 0) out[ZQTOT + 1 + n] = (float)rk[0];
}

__global__ void vq_final(const unsigned long long* __restrict__ acc, float* __restrict__ out) {
    if (threadIdx.x == 0 && blockIdx.x == 0) {
        double mse = (double)(long long)acc[0] / LOSS_SCALE / (double)ZQTOT;
        out[ZQTOT] = (float)(mse * 1.25);   // (1 + beta) * mse
    }
}

extern "C" void kernel_launch(void* const* d_in, const int* in_sizes, int n_in,
                              void* d_out, int out_size, void* d_ws, size_t ws_size,
                              hipStream_t stream) {
    const float* z   = (const float*)d_in[0];
    const float* emb = (const float*)d_in[1];
    float* out = (float*)d_out;

    unsigned long long* loss_acc = (unsigned long long*)d_ws;
    unsigned int* amb_cnt = (unsigned int*)((char*)d_ws + 8);
    const size_t WL4_OFF  = 64;
    const size_t ESQ_OFF  = (WL4_OFF + (size_t)MAX_AMB * 16 + 255) & ~(size_t)255;
    const size_t EMBH_OFF = (ESQ_OFF + (size_t)KCODES * 4 + 255) & ~(size_t)255;
    const size_t WS_NEED  = EMBH_OFF + (size_t)KCODES * CDIM * 2;

    hipMemsetAsync(d_ws, 0, 16, stream);
    if (ws_size >= WS_NEED) {
        uint4* wl4 = (uint4*)((char*)d_ws + WL4_OFF);
        float* esq_g = (float*)((char*)d_ws + ESQ_OFF);
        unsigned short* embh = (unsigned short*)((char*)d_ws + EMBH_OFF);
        vq_prep<<<dim3(KCODES), dim3(64), 0, stream>>>(emb, embh, esq_g);
        vq_main_mfma<<<dim3(NQ / QT2), dim3(256), 0, stream>>>(z, emb, embh, esq_g,
                                                               out, loss_acc, amb_cnt, wl4);
        vq_fix_cand<<<dim3(2048), dim3(64), 0, stream>>>(z, emb, out, amb_cnt, wl4);
    } else {
        unsigned int* wl = (unsigned int*)((char*)d_ws + WL4_OFF);
        vq_main_basic<<<dim3(NQ / 64), dim3(256), 0, stream>>>(z, emb, out, loss_acc, amb_cnt, wl);
        vq_fix_np<<<dim3(MAX_AMB), dim3(256), 0, stream>>>(z, emb, out, amb_cnt, wl);
    }
    vq_final<<<dim3(1), dim3(64), 0, stream>>>(loss_acc, out);
}

// Round 11
// 131.762 us; speedup vs baseline: 1.6806x; 1.3475x over previous
//
#include <hip/hip_runtime.h>

#define KCODES 1024
#define CDIM   256
#define SP     16384           // D*H*W
#define ZQTOT  16777216        // B*C*D*H*W
#define NQ     65536           // B*D*H*W
#define BSTRIDE 4194304        // C*SP
#define MAX_AMB 12288
#define LOSS_SCALE 33554432.0  // 2^25 fixed-point deterministic loss
#define KEYMASK 0xFFFFFC00u
#define AMB_THR 6.0e-4f

#define QT2    128             // queries per block (main kernel)
#define NTILE  32              // 32 code-tiles of 32 codes
#define ROWB   528             // padded LDS bytes per code row (33*16)
#define TILEB  16896           // 32*528

using f32x4  = __attribute__((ext_vector_type(4)))  float;
using f32x16 = __attribute__((ext_vector_type(16))) float;
using bf16x8 = __attribute__((ext_vector_type(8)))  short;

__device__ __forceinline__ unsigned short f2bf(float x) {   // RNE f32->bf16
    unsigned u = __float_as_uint(x);
    u += 0x7fffu + ((u >> 16) & 1u);
    return (unsigned short)(u >> 16);
}
__device__ __forceinline__ unsigned fkey(float s) {         // monotone f32->u32
    unsigned u = __float_as_uint(s);
    return u ^ ((unsigned)((int)u >> 31) | 0x80000000u);
}
__device__ __forceinline__ float funkey(unsigned k) {
    return (k & 0x80000000u) ? __uint_as_float(k ^ 0x80000000u)
                             : __uint_as_float(~k);
}
__device__ __forceinline__ unsigned umn(unsigned a, unsigned b){ return a < b ? a : b; }
__device__ __forceinline__ unsigned umx(unsigned a, unsigned b){ return a > b ? a : b; }

// ---- numpy pairwise_sum replication (base case n=128, 8 accumulators) ----
__device__ __forceinline__ float pw128_sq(const float* a) {
    float r[8];
    #pragma unroll
    for (int j = 0; j < 8; ++j) r[j] = __fmul_rn(a[j], a[j]);
    for (int i = 8; i < 128; i += 8) {
        #pragma unroll
        for (int j = 0; j < 8; ++j) r[j] = __fadd_rn(r[j], __fmul_rn(a[i+j], a[i+j]));
    }
    return __fadd_rn(__fadd_rn(__fadd_rn(r[0], r[1]), __fadd_rn(r[2], r[3])),
                     __fadd_rn(__fadd_rn(r[4], r[5]), __fadd_rn(r[6], r[7])));
}
__device__ __forceinline__ float pairwise256_sq(const float* a) {
    return __fadd_rn(pw128_sq(a), pw128_sq(a + 128));
}
// np.einsum SSE path: 4 mod-4 accumulators, separate mul/add roundings
__device__ __forceinline__ float np_dot256(const float* zr, const float* er) {
    float a0 = 0.f, a1 = 0.f, a2 = 0.f, a3 = 0.f;
    for (int i8 = 0; i8 < 256; i8 += 8) {
        a0 = __fadd_rn(a0, __fmul_rn(zr[i8+0], er[i8+0]));
        a1 = __fadd_rn(a1, __fmul_rn(zr[i8+1], er[i8+1]));
        a2 = __fadd_rn(a2, __fmul_rn(zr[i8+2], er[i8+2]));
        a3 = __fadd_rn(a3, __fmul_rn(zr[i8+3], er[i8+3]));
        a0 = __fadd_rn(a0, __fmul_rn(zr[i8+4], er[i8+4]));
        a1 = __fadd_rn(a1, __fmul_rn(zr[i8+5], er[i8+5]));
        a2 = __fadd_rn(a2, __fmul_rn(zr[i8+6], er[i8+6]));
        a3 = __fadd_rn(a3, __fmul_rn(zr[i8+7], er[i8+7]));
    }
    return __fadd_rn(__fadd_rn(a0, a1), __fadd_rn(a2, a3));
}

// ---------------- pre-pass: emb -> bf16 (hi only) + esq ----------------
__global__ __launch_bounds__(64)
void vq_prep(const float* __restrict__ emb, unsigned short* __restrict__ embh,
             float* __restrict__ esq_g) {
    const int k = blockIdx.x;
    const int l = threadIdx.x;
    float4 v = ((const float4*)(emb + (size_t)k * CDIM))[l];
    float s = v.x*v.x + v.y*v.y + v.z*v.z + v.w*v.w;
    unsigned short h0=f2bf(v.x), h1=f2bf(v.y), h2=f2bf(v.z), h3=f2bf(v.w);
    uint2 hh; hh.x = (unsigned)h0 | ((unsigned)h1<<16); hh.y = (unsigned)h2 | ((unsigned)h3<<16);
    *(uint2*)&embh[(size_t)k*CDIM + l*4] = hh;
    #pragma unroll
    for (int off = 32; off > 0; off >>= 1) s += __shfl_down(s, off, 64);
    if (l == 0) esq_g[k] = s;
}

// ------- MFMA main: r10 structure + 4 acc chains + single barrier/tile -------
__global__ __launch_bounds__(256, 2)
void vq_main_mfma(const float* __restrict__ z, const float* __restrict__ emb,
                  const unsigned short* __restrict__ embh,
                  const float* __restrict__ esq_g,
                  float* __restrict__ out, unsigned long long* __restrict__ loss_acc,
                  unsigned int* __restrict__ amb_cnt, uint4* __restrict__ wl4) {
    __shared__ __align__(16) unsigned char smem[2*TILEB + 4096];
    unsigned* top1 = (unsigned*)(smem + 2*TILEB);          // 128 u32
    unsigned* top2 = top1 + 128;
    unsigned* top3 = top2 + 128;
    float*    zsql = (float*)(top3 + 128);                 // 128 f32
    int*      fidx = (int*)(zsql + 128);                   // 128 i32
    float*    lpart = (float*)(fidx + 128);                // 2 f32

    const int t    = threadIdx.x;
    const int l    = t & 63;
    const int w    = t >> 6;
    const int half = l >> 5;
    const int lr   = l & 31;
    // XCD-bijective swizzle (nwg=512, 512%8==0)
    const int bid  = blockIdx.x;
    const int obid = ((bid & 7) << 6) + (bid >> 3);
    const int n0   = obid * QT2;
    const int b    = n0 >> 14;
    const int sp0  = n0 & 16383;
    const int wq0  = w * 32;
    const float* zb = z + (size_t)b * BSTRIDE + sp0 + wq0 + lr;

    // ---- issue tile-0 B stage loads (latency covered by A-load below) ----
    uint4 st[4];
    const char* ebase = (const char*)embh;
    #pragma unroll
    for (int k = 0; k < 4; ++k)
        st[k] = *(const uint4*)(ebase + (size_t)(t + k*256) * 16);

    // ---- A fragments in registers: lane = query (lr), k-half (half) ----
    bf16x8 A[16];
    float zsq_p = 0.f;
    #pragma unroll
    for (int ks = 0; ks < 16; ++ks) {
        const float* zp = zb + (size_t)(ks*16 + half*8) * SP;
        float v[8];
        #pragma unroll
        for (int j = 0; j < 8; ++j) v[j] = zp[(size_t)j * SP];
        bf16x8 a;
        #pragma unroll
        for (int j = 0; j < 8; ++j) {
            zsq_p += v[j] * v[j];
            a[j] = (short)f2bf(v[j]);
        }
        A[ks] = a;
    }
    zsq_p += __shfl_xor(zsq_p, 32, 64);
    if (half == 0) zsql[wq0 + lr] = zsq_p;

    // ---- write tile 0 into LDS buffer 0 (padded rows) ----
    #pragma unroll
    for (int k = 0; k < 4; ++k) {
        const int idx = t + k*256;
        *(uint4*)(smem + (idx >> 5)*ROWB + (idx & 31)*16) = st[k];
    }
    __syncthreads();

    unsigned m1v[16], m2v[16], m3v[16];
    #pragma unroll
    for (int s = 0; s < 16; ++s) { m1v[s]=0xFFFFFFFFu; m2v[s]=0xFFFFFFFFu; m3v[s]=0xFFFFFFFFu; }

    int cur = 0;
    for (int tile = 0; tile < NTILE; ++tile) {
        // prefetch next tile's B into registers (issue early: MFMA phase covers)
        if (tile + 1 < NTILE) {
            #pragma unroll
            for (int k = 0; k < 4; ++k)
                st[k] = *(const uint4*)(ebase + (size_t)(tile+1)*16384 + (size_t)(t + k*256)*16);
        }
        const float es = esq_g[tile*32 + lr];

        // ---- 4 independent MFMA chains (ks mod 4) -> 4x less dep-stall ----
        const unsigned char* bb = smem + cur*TILEB + lr*ROWB + half*16;
        f32x16 acc[4];
        #pragma unroll
        for (int c = 0; c < 4; ++c)
            acc[c] = f32x16{0.f,0.f,0.f,0.f,0.f,0.f,0.f,0.f,0.f,0.f,0.f,0.f,0.f,0.f,0.f,0.f};
        #pragma unroll
        for (int ks = 0; ks < 16; ++ks) {
            const bf16x8 Bv = *(const bf16x8*)(bb + ks*32);
            acc[ks & 3] = __builtin_amdgcn_mfma_f32_32x32x16_bf16(A[ks], Bv, acc[ks & 3], 0, 0, 0);
        }
        // fold: lane's code = tile*32+lr; reg s = query row (s&3)+8*(s>>2)+4*half
        const unsigned kc = (unsigned)(tile*32 + lr);
        #pragma unroll
        for (int s = 0; s < 16; ++s) {
            const float dot = (acc[0][s] + acc[1][s]) + (acc[2][s] + acc[3][s]);
            const float sc = __builtin_fmaf(-2.0f, dot, es);
            const unsigned p = (fkey(sc) & KEYMASK) | kc;
            const unsigned x = umx(m1v[s], p); m1v[s] = umn(m1v[s], p);
            const unsigned y = umx(m2v[s], x); m2v[s] = umn(m2v[s], x);
            m3v[s] = umn(m3v[s], y);
        }
        // write next tile into the other buffer, then ONE barrier.
        // Safety: write_i(buf X) vs read_{i-1}(buf X) are separated by barrier_{i-1};
        // within an iteration reads hit cur, writes hit cur^1 (disjoint).
        if (tile + 1 < NTILE) {
            #pragma unroll
            for (int k = 0; k < 4; ++k) {
                const int idx = t + k*256;
                *(uint4*)(smem + (cur^1)*TILEB + (idx >> 5)*ROWB + (idx & 31)*16) = st[k];
            }
        }
        __syncthreads();
        cur ^= 1;
    }

    // ---- butterfly merge of top-3 across the 32 lanes of each half-wave ----
    #pragma unroll
    for (int s = 0; s < 16; ++s) {
        unsigned a1 = m1v[s], a2 = m2v[s], a3 = m3v[s];
        #pragma unroll
        for (int m = 1; m < 32; m <<= 1) {
            const unsigned b1 = (unsigned)__shfl_xor((int)a1, m, 64);
            const unsigned b2 = (unsigned)__shfl_xor((int)a2, m, 64);
            const unsigned b3 = (unsigned)__shfl_xor((int)a3, m, 64);
            const unsigned hi1 = umx(a1, b1), lo2 = umn(a2, b2);
            const unsigned r3  = umn(umx(hi1, lo2), umn(a3, b3));
            a1 = umn(a1, b1);
            a2 = umn(hi1, lo2);
            a3 = r3;
        }
        if (lr == s) {
            const int r = (s & 3) + ((s >> 2) << 3) + (half << 2);
            top1[wq0 + r] = a1; top2[wq0 + r] = a2; top3[wq0 + r] = a3;
        }
    }
    __syncthreads();

    // ---- per-query finalize: idx, ambiguity enqueue, loss ----
    if (t < QT2) {
        const unsigned k1 = top1[t], k2 = top2[t], k3 = top3[t];
        const int I1 = (int)(k1 & 1023u);
        fidx[t] = I1;
        out[ZQTOT + 1 + n0 + t] = (float)I1;
        const float s0 = funkey(k1 & KEYMASK);
        if (funkey(k2 & KEYMASK) - s0 < AMB_THR) {
            unsigned pos = atomicAdd(amb_cnt, 1u);
            if (pos < MAX_AMB)
                wl4[pos] = make_uint4((unsigned)(n0 + t),
                                      (k1 & 1023u) | ((k2 & 1023u) << 16),
                                      (k3 & 1023u) | ((k3 & 1023u) << 16), 0u);
        }
        float lq = zsql[t] + s0;         // ||z-e||^2 = zsq + (esq - 2 dot)
        #pragma unroll
        for (int off = 32; off > 0; off >>= 1) lq += __shfl_down(lq, off, 64);
        if ((t & 63) == 0) lpart[t >> 6] = lq;
    }
    __syncthreads();
    if (t == 0)
        atomicAdd(loss_acc, (unsigned long long)(long long)((double)(lpart[0] + lpart[1]) * LOSS_SCALE));

    // ---- z_q write: stream emb[fidx] rows (STE output == e, tol 20.48) ----
    {
        const int q  = t & 127;
        const int dh = t >> 7;
        const int fq = fidx[q];
        const float4* ev = (const float4*)(emb + (size_t)fq * CDIM + dh * 128);
        float* ob = out + (size_t)b * BSTRIDE + (size_t)dh * 128 * SP + sp0 + q;
        #pragma unroll
        for (int i = 0; i < 32; ++i) {
            const float4 v = ev[i];
            float* o = ob + (size_t)(i * 4) * SP;
            o[0]            = v.x;
            o[SP]           = v.y;
            o[2*SP]         = v.z;
            o[(size_t)3*SP] = v.w;
        }
    }
}

// ---------------- fixup: wave-parallel np-exact, grid-stride over worklist ----------------
__global__ __launch_bounds__(64)
void vq_fix_cand(const float* __restrict__ z, const float* __restrict__ emb,
                 float* __restrict__ out, const unsigned int* __restrict__ amb_cnt,
                 const uint4* __restrict__ wl4) {
    __shared__ float zrow[CDIM];
    __shared__ float erow[4][CDIM];
    __shared__ float dsh[4], esh[4];
    __shared__ float zss;

    unsigned cnt = *amb_cnt; if (cnt > MAX_AMB) cnt = MAX_AMB;
    const int l = threadIdx.x;

    for (unsigned widx = blockIdx.x; widx < cnt; widx += gridDim.x) {
        __syncthreads();    // protect LDS reuse across iterations
        const uint4 e = wl4[widx];
        const int n = (int)e.x;
        const int b = n >> 14, sp = n & 16383;
        int codes[4] = { (int)(e.y & 1023u), (int)((e.y >> 16) & 1023u),
                         (int)(e.z & 1023u), (int)((e.z >> 16) & 1023u) };

        #pragma unroll
        for (int i = 0; i < 4; ++i) {
            const int c = l + 64*i;
            zrow[c] = z[(size_t)b * BSTRIDE + (size_t)c * SP + sp];
        }
        {
            const int r = l >> 4, c0 = (l & 15) * 16;
            const float4* src = (const float4*)(emb + (size_t)codes[r] * CDIM + c0);
            float4* dst = (float4*)&erow[r][c0];
            #pragma unroll
            for (int i = 0; i < 4; ++i) dst[i] = src[i];
        }
        __syncthreads();

        const int role = l >> 4, rr = (l >> 2) & 3, a = l & 3;
        if (role == 0) {
            const float* er = erow[rr];
            float acc = __fmul_rn(zrow[a], er[a]);
            for (int i = 1; i < 64; ++i)
                acc = __fadd_rn(acc, __fmul_rn(zrow[4*i + a], er[4*i + a]));
            const float u = __fadd_rn(acc, __shfl_xor(acc, 1, 64));
            const float d = __fadd_rn(u,   __shfl_xor(u,   2, 64));  // (a0+a1)+(a2+a3)
            if (a == 0) dsh[rr] = d;
        } else if (role == 1 || (role == 2 && rr == 0)) {
            const float* src = (role == 1) ? erow[rr] : zrow;
            float pA = __fmul_rn(src[a],       src[a]);
            float pB = __fmul_rn(src[a+4],     src[a+4]);
            float qA = __fmul_rn(src[128+a],   src[128+a]);
            float qB = __fmul_rn(src[128+a+4], src[128+a+4]);
            #pragma unroll 4
            for (int i = 1; i < 16; ++i) {
                pA = __fadd_rn(pA, __fmul_rn(src[8*i+a],       src[8*i+a]));
                pB = __fadd_rn(pB, __fmul_rn(src[8*i+a+4],     src[8*i+a+4]));
                qA = __fadd_rn(qA, __fmul_rn(src[128+8*i+a],   src[128+8*i+a]));
                qB = __fadd_rn(qB, __fmul_rn(src[128+8*i+a+4], src[128+8*i+a+4]));
            }
            float uA = __fadd_rn(pA, __shfl_xor(pA, 1, 64));
            float vA = __fadd_rn(uA, __shfl_xor(uA, 2, 64));
            float uB = __fadd_rn(pB, __shfl_xor(pB, 1, 64));
            float vB = __fadd_rn(uB, __shfl_xor(uB, 2, 64));
            const float h0 = __fadd_rn(vA, vB);
            float uC = __fadd_rn(qA, __shfl_xor(qA, 1, 64));
            float vC = __fadd_rn(uC, __shfl_xor(uC, 2, 64));
            float uD = __fadd_rn(qB, __shfl_xor(qB, 1, 64));
            float vD = __fadd_rn(uD, __shfl_xor(uD, 2, 64));
            const float h1 = __fadd_rn(vC, vD);
            const float stot = __fadd_rn(h0, h1);
            if (a == 0) { if (role == 1) esh[rr] = stot; else zss = stot; }
        }
        __syncthreads();
        if (l == 0) {
            float bd = 3.4e38f; int bk = KCODES;
            #pragma unroll
            for (int i = 0; i < 4; ++i) {
                const float d = __fsub_rn(__fadd_rn(zss, esh[i]), __fmul_rn(2.0f, dsh[i]));
                if (d < bd || (d == bd && codes[i] < bk)) { bd = d; bk = codes[i]; }
            }
            out[ZQTOT + 1 + n] = (float)bk;   // np.argmin first-index semantics
        }
    }
}

// ---------------- fallback (round-3 proven path, used if ws too small) ----------------
__global__ __launch_bounds__(256)
void vq_main_basic(const float* __restrict__ z, const float* __restrict__ emb,
                   float* __restrict__ out, unsigned long long* __restrict__ loss_acc,
                   unsigned int* __restrict__ amb_cnt, unsigned int* __restrict__ wl) {
    __shared__ float zlz[64 * CDIM];
    __shared__ float esq[KCODES];
    __shared__ float m1s[4][64], m2s[4][64];
    __shared__ int   i1s[4][64];
    __shared__ int   fidx[64];
    __shared__ float lsum[4];

    const int t  = threadIdx.x;
    const int q  = t & 63;
    const int w  = __builtin_amdgcn_readfirstlane(t >> 6);
    const int qs = q & 7;
    const int n0 = blockIdx.x * 64;
    const int b  = n0 >> 14;
    const int sp0 = n0 & 16383;
    const float* zb = z + (size_t)b * BSTRIDE;

    #pragma unroll 4
    for (int i = 0; i < 64; ++i) {
        int c = (t >> 6) * 64 + i;
        float v = zb[(size_t)c * SP + sp0 + q];
        zlz[q * CDIM + ((((c >> 2) ^ qs) << 2) | (c & 3))] = v;
    }
    for (int k = t; k < KCODES; k += 256) {
        const float4* er = (const float4*)(emb + (size_t)k * CDIM);
        float s = 0.f;
        for (int c4 = 0; c4 < 64; ++c4) {
            float4 e = er[c4];
            s += e.x*e.x + e.y*e.y + e.z*e.z + e.w*e.w;
        }
        esq[k] = s;
    }
    __syncthreads();

    float m1 = 3.4e38f, m2 = 3.4e38f; int i1 = 0;
    const float* zrow = zlz + q * CDIM;
    const int kbase = w * 256;
    for (int kk = 0; kk < 256; kk += 8) {
        const int k0 = kbase + kk;
        float acc[8] = {0,0,0,0,0,0,0,0};
        for (int c4 = 0; c4 < 64; ++c4) {
            float4 zv = *(const float4*)(zrow + ((c4 ^ qs) << 2));
            #pragma unroll
            for (int j = 0; j < 8; ++j) {
                float4 ev = *(const float4*)(emb + (size_t)(k0 + j) * CDIM + (c4 << 2));
                acc[j] += zv.x*ev.x + zv.y*ev.y + zv.z*ev.z + zv.w*ev.w;
            }
        }
        #pragma unroll
        for (int j = 0; j < 8; ++j) {
            float s = esq[k0 + j] - 2.0f * acc[j];
            if (s < m1)      { m2 = m1; m1 = s; i1 = k0 + j; }
            else if (s < m2) { m2 = s; }
        }
    }
    m1s[w][q] = m1; m2s[w][q] = m2; i1s[w][q] = i1;
    __syncthreads();

    if (t < 64) {
        float M1 = 3.4e38f, M2 = 3.4e38f; int I1 = 0;
        for (int g = 0; g < 4; ++g) {
            float v1 = m1s[g][t], v2 = m2s[g][t];
            int   a1 = i1s[g][t];
            if (v1 < M1) { M2 = M1; M1 = v1; I1 = a1; }
            else if (v1 < M2) { M2 = v1; }
            if (v2 < M2) { M2 = v2; }
        }
        if (M2 - M1 < 1.5e-4f) {
            unsigned pos = atomicAdd(amb_cnt, 1u);
            if (pos < MAX_AMB) wl[pos] = n0 + t;
        }
        fidx[t] = I1;
        out[ZQTOT + 1 + n0 + t] = (float)I1;
    }
    __syncthreads();

    const int fq = fidx[q];
    const float* eq = emb + (size_t)fq * CDIM;
    float ls = 0.f;
    #pragma unroll 4
    for (int i = 0; i < 64; ++i) {
        int c = (t >> 6) * 64 + i;
        float zv = zrow[((((c >> 2) ^ qs) << 2) | (c & 3))];
        float ev = eq[c];
        float d = ev - zv;
        ls += d * d;
        out[(size_t)b * BSTRIDE + (size_t)c * SP + sp0 + q] = zv + d;
    }
    #pragma unroll
    for (int off = 32; off > 0; off >>= 1) ls += __shfl_down(ls, off, 64);
    if (q == 0) lsum[w] = ls;
    __syncthreads();
    if (t == 0) {
        float tot = lsum[0] + lsum[1] + lsum[2] + lsum[3];
        atomicAdd(loss_acc, (unsigned long long)(long long)((double)tot * LOSS_SCALE));
    }
}

__global__ __launch_bounds__(256)
void vq_fix_np(const float* __restrict__ z, const float* __restrict__ emb,
               float* __restrict__ out, const unsigned int* __restrict__ amb_cnt,
               const unsigned int* __restrict__ wl) {
    __shared__ float zrow[CDIM];
    __shared__ float zsq_sh;
    __shared__ float rd[256];
    __shared__ int   rk[256];

    unsigned cnt = *amb_cnt; if (cnt > MAX_AMB) cnt = MAX_AMB;
    if (blockIdx.x >= cnt) return;
    const int n = (int)wl[blockIdx.x];
    const int b = n >> 14, sp = n & 16383;
    const int t = threadIdx.x;

    zrow[t] = z[(size_t)b * BSTRIDE + (size_t)t * SP + sp];
    __syncthreads();
    if (t == 0) zsq_sh = pairwise256_sq(zrow);
    __syncthreads();
    const float zsq = zsq_sh;

    float bestd = 3.4e38f; int bestk = KCODES;
    for (int j = 0; j < 4; ++j) {
        const int k = t + 256 * j;
        const float* er = emb + (size_t)k * CDIM;
        const float dot = np_dot256(zrow, er);
        const float es  = pairwise256_sq(er);
        const float d   = __fsub_rn(__fadd_rn(zsq, es), __fmul_rn(2.0f, dot));
        if (d < bestd || (d == bestd && k < bestk)) { bestd = d; bestk = k; }
    }
    rd[t] = bestd; rk[t] = bestk;
    __syncthreads();
    for (int s = 128; s > 0; s >>= 1) {
        if (t < s) {
            float od = rd[t + s]; int ok = rk[t + s];
            if (od < rd[t] || (od == rd[t] && ok < rk[t])) { rd[t] = od; rk[t] = ok; }
        }
        __syncthreads();
    }
    if (t == 0) out[ZQTOT + 1 + n] = (float)rk[0];
}

__global__ void vq_final(const unsigned long long* __restrict__ acc, float* __restrict__ out) {
    if (threadIdx.x == 0 && blockIdx.x == 0) {
        double mse = (double)(long long)acc[0] / LOSS_SCALE / (double)ZQTOT;
        out[ZQTOT] = (float)(mse * 1.25);   // (1 + beta) * mse
    }
}

extern "C" void kernel_launch(void* const* d_in, const int* in_sizes, int n_in,
                              void* d_out, int out_size, void* d_ws, size_t ws_size,
                              hipStream_t stream) {
    const float* z   = (const float*)d_in[0];
    const float* emb = (const float*)d_in[1];
    float* out = (float*)d_out;

    unsigned long long* loss_acc = (unsigned long long*)d_ws;
    unsigned int* amb_cnt = (unsigned int*)((char*)d_ws + 8);
    const size_t WL4_OFF  = 64;
    const size_t ESQ_OFF  = (WL4_OFF + (size_t)MAX_AMB * 16 + 255) & ~(size_t)255;
    const size_t EMBH_OFF = (ESQ_OFF + (size_t)KCODES * 4 + 255) & ~(size_t)255;
    const size_t WS_NEED  = EMBH_OFF + (size_t)KCODES * CDIM * 2;

    hipMemsetAsync(d_ws, 0, 16, stream);
    if (ws_size >= WS_NEED) {
        uint4* wl4 = (uint4*)((char*)d_ws + WL4_OFF);
        float* esq_g = (float*)((char*)d_ws + ESQ_OFF);
        unsigned short* embh = (unsigned short*)((char*)d_ws + EMBH_OFF);
        vq_prep<<<dim3(KCODES), dim3(64), 0, stream>>>(emb, embh, esq_g);
        vq_main_mfma<<<dim3(NQ / QT2), dim3(256), 0, stream>>>(z, emb, embh, esq_g,
                                                               out, loss_acc, amb_cnt, wl4);
        vq_fix_cand<<<dim3(2048), dim3(64), 0, stream>>>(z, emb, out, amb_cnt, wl4);
    } else {
        unsigned int* wl = (unsigned int*)((char*)d_ws + WL4_OFF);
        vq_main_basic<<<dim3(NQ / 64), dim3(256), 0, stream>>>(z, emb, out, loss_acc, amb_cnt, wl);
        vq_fix_np<<<dim3(MAX_AMB), dim3(256), 0, stream>>>(z, emb, out, amb_cnt, wl);
    }
    vq_final<<<dim3(1), dim3(64), 0, stream>>>(loss_acc, out);
}